// Round 7
// baseline (687.424 us; speedup 1.0000x reference)
//
#include <hip/hip_runtime.h>
#include <cstddef>
#include <cstdint>

// Problem constants (fixed by reference setup_inputs)
constexpr int NN = 16, CC = 256, HH = 64, WW = 64, HW = 64 * 64; // 4096
constexpr size_t FSZ = (size_t)NN * CC * HW;                      // 16,777,216

typedef short bf16x8 __attribute__((ext_vector_type(8)));
typedef float f32x4 __attribute__((ext_vector_type(4)));

__device__ __forceinline__ float sigmoidf_(float x) { return 1.f / (1.f + expf(-x)); }

__device__ __forceinline__ unsigned short bf16_rne(float f) {
    uint32_t u = __builtin_bit_cast(uint32_t, f);
    u += 0x7FFFu + ((u >> 16) & 1u);
    return (unsigned short)(u >> 16);
}
__device__ __forceinline__ float bf16_tof(unsigned short h) {
    uint32_t u = ((uint32_t)h) << 16;
    return __builtin_bit_cast(float, u);
}

// Direct global->LDS DMA, 16B per lane. LDS dest = wave-uniform base + lane*16.
__device__ __forceinline__ void gload16(const void* g, void* l) {
    __builtin_amdgcn_global_load_lds((const __attribute__((address_space(1))) void*)g,
                                     (__attribute__((address_space(3))) void*)l, 16, 0, 0);
}

// ---------------------------------------------------------------------------
// W fragment-order layout (A-operand), logical (o, k) of a 256x256 matrix:
//   elem = ((o>>4)*8 + (k>>5))*512 + ((k&31)>>3)*128 + (o&15)*8 + (k&7)
// A wave reads one 16(o)x32(k) fragment as base + lane*8 ushorts (R3-verified).
//
// R7 geometry: BK=64 (4 barriers/block instead of 8) and, for conv1/conv2,
// o-tile 256 (one block covers all outputs; per-barrier MFMA phase = 192/wave
// ~ 960cy >= HBM latency, so the vmcnt(0) drain at the barrier is covered).
// X staged via global_load_lds into double-buffered linear LDS [64][64]us
// (128B rows, 8 chunks of 16B). XOR swizzle: chunk c of row r lives at slot
// c^(r&7); produced by PRE-SWIZZLING the per-lane GLOBAL source address
// (LDS writes stay linear), consumed by swizzled ds_read slot. Involution ->
// correct; 16 lanes hit 8 bank-quads x2 -> 2-way (free). (R6-verified scheme,
// generalized from 4 to 8 chunks/row.)
// ---------------------------------------------------------------------------

// ---------------------------------------------------------------------------
// Weight split -> fragment order. Also zeroes sum_c/sq_c and s_pix.
// ---------------------------------------------------------------------------
__global__ __launch_bounds__(256) void wsplit_kernel(
    const float* __restrict__ w1, const float* __restrict__ w2,
    const float* __restrict__ w3, const float* __restrict__ w4,
    unsigned short* __restrict__ w1h, unsigned short* __restrict__ w1m, unsigned short* __restrict__ w1l,
    unsigned short* __restrict__ w2h, unsigned short* __restrict__ w2m, unsigned short* __restrict__ w2l,
    unsigned short* __restrict__ w4h, unsigned short* __restrict__ w4l,
    unsigned short* __restrict__ w3b,
    float* __restrict__ zstat, float* __restrict__ zspix) {
    const int i = blockIdx.x * 256 + threadIdx.x;  // 65536 weights each
    const int o = i >> 8, c = i & 255;
    const size_t fo = ((size_t)((o >> 4) * 8 + (c >> 5))) * 512 +
                      (size_t)(((c & 31) >> 3) * 128 + (o & 15) * 8 + (c & 7));
    {
        float x = w1[i];
        unsigned short h = bf16_rne(x); float r = x - bf16_tof(h);
        unsigned short m = bf16_rne(r); float r2 = r - bf16_tof(m);
        w1h[fo] = h; w1m[fo] = m; w1l[fo] = bf16_rne(r2);
    }
    {
        float x = w2[i];
        unsigned short h = bf16_rne(x); float r = x - bf16_tof(h);
        unsigned short m = bf16_rne(r); float r2 = r - bf16_tof(m);
        w2h[fo] = h; w2m[fo] = m; w2l[fo] = bf16_rne(r2);
    }
    {
        float x = w4[i];
        unsigned short h = bf16_rne(x); float r = x - bf16_tof(h);
        w4h[fo] = h; w4l[fo] = bf16_rne(r);
    }
    w3b[fo] = bf16_rne(w3[i]);
    if (i < 8192) zstat[i] = 0.f;   // sum_c (4096) + sq_c (4096), contiguous
    zspix[i] = 0.f;                 // s_pix (harmless; now plain-stored)
}

// ---------------------------------------------------------------------------
// Transpose + split: X fp32 [n][C][HW] -> NS bf16 arrays [n][HW][C]
// grid (HW/64, C/64, N), 256 threads
// ---------------------------------------------------------------------------
template <int NS>
__global__ __launch_bounds__(256) void tsplit_kernel(const float* __restrict__ X,
                                                     unsigned short* __restrict__ O0,
                                                     unsigned short* __restrict__ O1,
                                                     unsigned short* __restrict__ O2) {
    const int hw0 = blockIdx.x * 64, c0 = blockIdx.y * 64, n = blockIdx.z;
    __shared__ float sT[64][65];
    const int tid = threadIdx.x;
    {
        const int hwl = (tid & 15) << 2;
        const int cl = tid >> 4;  // 0..15
#pragma unroll
        for (int p = 0; p < 4; ++p) {
            const int c = cl + p * 16;
            const float4 v = *(const float4*)(X + ((size_t)(n * CC + c0 + c)) * HW + hw0 + hwl);
            sT[c][hwl] = v.x; sT[c][hwl + 1] = v.y; sT[c][hwl + 2] = v.z; sT[c][hwl + 3] = v.w;
        }
    }
    __syncthreads();
    const int hwl = tid >> 2, cb = (tid & 3) << 4;
    unsigned short h[16], m[16], l[16];
#pragma unroll
    for (int j = 0; j < 16; ++j) {
        const float x = sT[cb + j][hwl];
        const unsigned short hh = bf16_rne(x);
        h[j] = hh;
        if (NS >= 2) {
            const float r = x - bf16_tof(hh);
            const unsigned short mm = bf16_rne(r);
            m[j] = mm;
            if (NS >= 3) l[j] = bf16_rne(r - bf16_tof(mm));
        }
    }
    const size_t ob = ((size_t)(n * HW + hw0 + hwl)) * 256 + c0 + cb;
    *(int4*)(O0 + ob) = *(int4*)&h[0]; *(int4*)(O0 + ob + 8) = *(int4*)&h[8];
    if (NS >= 2) { *(int4*)(O1 + ob) = *(int4*)&m[0]; *(int4*)(O1 + ob + 8) = *(int4*)&m[8]; }
    if (NS >= 3) { *(int4*)(O2 + ob) = *(int4*)&l[0]; *(int4*)(O2 + ob + 8) = *(int4*)&l[8]; }
}

// ---------------------------------------------------------------------------
// MFMA GEMM core v7 (conv1/conv2): o-tile 256, BK=64, 4 k-tiles, 4 waves.
// Wave wv owns o in [wv*64, wv*64+64). 192 MFMA per wave per barrier.
// acc[f][nt]: o = wv*64 + f*16 + quad*4 + reg, hw = hw0 + nt*16 + (lane&15)
// ---------------------------------------------------------------------------
__device__ __forceinline__ void mfma_core7(const unsigned short* __restrict__ X0,
                                           const unsigned short* __restrict__ X1,
                                           const unsigned short* __restrict__ X2,
                                           const unsigned short* __restrict__ W0,
                                           const unsigned short* __restrict__ W1,
                                           const unsigned short* __restrict__ W2,
                                           int n, int hw0, f32x4 (&acc)[4][4]) {
    __shared__ unsigned short sX[2][3][64][64];   // 48 KB, linear 128B rows
    const int tid = threadIdx.x;
    const int lane = tid & 63, wv = tid >> 6, quad = lane >> 4, nlo = lane & 15;
    const int srl = lane >> 3;                 // row within 8-row staging chunk
    const int sch = (lane & 7) ^ srl;          // pre-swizzled source chunk
    const unsigned short* Xs[3] = {X0, X1, X2};
    const unsigned short* Ws[3] = {W0, W1, W2};
    const size_t xgb = ((size_t)(n * HW + hw0 + wv * 16 + srl)) * 256 + sch * 8;
    const unsigned short* wp[3];
#pragma unroll
    for (int s = 0; s < 3; ++s)
        wp[s] = Ws[s] + ((size_t)(wv * 4) * 8) * 512 + (size_t)lane * 8;

    int roff[2][4];
#pragma unroll
    for (int s2 = 0; s2 < 2; ++s2)
#pragma unroll
        for (int nt = 0; nt < 4; ++nt) {
            const int rrow = nt * 16 + nlo;
            roff[s2][nt] = rrow * 64 + ((s2 * 4 + quad) ^ (rrow & 7)) * 8;
        }

    // prologue: stage k-tile 0
#pragma unroll
    for (int s = 0; s < 3; ++s)
#pragma unroll
        for (int j = 0; j < 2; ++j)
            gload16(Xs[s] + xgb + (size_t)j * 8 * 256, &sX[0][s][wv * 16 + j * 8][0]);
    __syncthreads();

#pragma unroll
    for (int kt = 0; kt < 4; ++kt) {
        const int cur = kt & 1;
        if (kt < 3) {
#pragma unroll
            for (int s = 0; s < 3; ++s)
#pragma unroll
                for (int j = 0; j < 2; ++j)
                    gload16(Xs[s] + xgb + (kt + 1) * 64 + (size_t)j * 8 * 256,
                            &sX[cur ^ 1][s][wv * 16 + j * 8][0]);
        }
#pragma unroll
        for (int s2 = 0; s2 < 2; ++s2) {
            const int kk = kt * 2 + s2;
            bf16x8 af[3][4];
#pragma unroll
            for (int s = 0; s < 3; ++s)
#pragma unroll
                for (int f = 0; f < 4; ++f)
                    af[s][f] = *(const bf16x8*)(wp[s] + ((size_t)(f * 8 + kk)) * 512);
#pragma unroll
            for (int nt = 0; nt < 4; ++nt) {
                bf16x8 bfr[3];
#pragma unroll
                for (int s = 0; s < 3; ++s)
                    bfr[s] = *(const bf16x8*)&sX[cur][s][0][roff[s2][nt]];
#pragma unroll
                for (int f = 0; f < 4; ++f) {
                    // smallest-magnitude-first order, identical to R6
                    acc[f][nt] = __builtin_amdgcn_mfma_f32_16x16x32_bf16(af[1][f], bfr[1], acc[f][nt], 0, 0, 0);
                    acc[f][nt] = __builtin_amdgcn_mfma_f32_16x16x32_bf16(af[0][f], bfr[2], acc[f][nt], 0, 0, 0);
                    acc[f][nt] = __builtin_amdgcn_mfma_f32_16x16x32_bf16(af[2][f], bfr[0], acc[f][nt], 0, 0, 0);
                    acc[f][nt] = __builtin_amdgcn_mfma_f32_16x16x32_bf16(af[0][f], bfr[1], acc[f][nt], 0, 0, 0);
                    acc[f][nt] = __builtin_amdgcn_mfma_f32_16x16x32_bf16(af[1][f], bfr[0], acc[f][nt], 0, 0, 0);
                    acc[f][nt] = __builtin_amdgcn_mfma_f32_16x16x32_bf16(af[0][f], bfr[0], acc[f][nt], 0, 0, 0);
                }
            }
        }
        __syncthreads();
    }
}

// ---------------------------------------------------------------------------
// Paired-product core v7 (merged conv4+conv3): o-tile 128, BK=64. acc_a gets
// conv4's 3 split-products, acc_b conv3's single product.
// ---------------------------------------------------------------------------
__device__ __forceinline__ void mfma_core_pair7(const unsigned short* __restrict__ XUH,
                                                const unsigned short* __restrict__ XUL,
                                                const unsigned short* __restrict__ XDW,
                                                const unsigned short* __restrict__ W4H,
                                                const unsigned short* __restrict__ W4L,
                                                const unsigned short* __restrict__ W3B,
                                                int n, int hw0, int o0,
                                                f32x4 (&acc_a)[2][4], f32x4 (&acc_b)[2][4]) {
    __shared__ unsigned short sX[2][3][64][64];
    const int tid = threadIdx.x;
    const int lane = tid & 63, wv = tid >> 6, quad = lane >> 4, nlo = lane & 15;
    const int srl = lane >> 3;
    const int sch = (lane & 7) ^ srl;
    const unsigned short* Xs[3] = {XUH, XUL, XDW};
    const unsigned short* Ws[3] = {W4H, W4L, W3B};
    const size_t xgb = ((size_t)(n * HW + hw0 + wv * 16 + srl)) * 256 + sch * 8;
    const unsigned short* wp[3];
#pragma unroll
    for (int s = 0; s < 3; ++s)
        wp[s] = Ws[s] + ((size_t)((o0 >> 4) + wv) * 8) * 512 + (size_t)lane * 8;

    int roff[2][4];
#pragma unroll
    for (int s2 = 0; s2 < 2; ++s2)
#pragma unroll
        for (int nt = 0; nt < 4; ++nt) {
            const int rrow = nt * 16 + nlo;
            roff[s2][nt] = rrow * 64 + ((s2 * 4 + quad) ^ (rrow & 7)) * 8;
        }

#pragma unroll
    for (int s = 0; s < 3; ++s)
#pragma unroll
        for (int j = 0; j < 2; ++j)
            gload16(Xs[s] + xgb + (size_t)j * 8 * 256, &sX[0][s][wv * 16 + j * 8][0]);
    __syncthreads();

#pragma unroll
    for (int kt = 0; kt < 4; ++kt) {
        const int cur = kt & 1;
        if (kt < 3) {
#pragma unroll
            for (int s = 0; s < 3; ++s)
#pragma unroll
                for (int j = 0; j < 2; ++j)
                    gload16(Xs[s] + xgb + (kt + 1) * 64 + (size_t)j * 8 * 256,
                            &sX[cur ^ 1][s][wv * 16 + j * 8][0]);
        }
#pragma unroll
        for (int s2 = 0; s2 < 2; ++s2) {
            const int kk = kt * 2 + s2;
            bf16x8 af[3][2];
#pragma unroll
            for (int s = 0; s < 3; ++s)
#pragma unroll
                for (int f = 0; f < 2; ++f)
                    af[s][f] = *(const bf16x8*)(wp[s] + ((size_t)(f * 32 + kk)) * 512);
#pragma unroll
            for (int nt = 0; nt < 4; ++nt) {
                bf16x8 bfr[3];
#pragma unroll
                for (int s = 0; s < 3; ++s)
                    bfr[s] = *(const bf16x8*)&sX[cur][s][0][roff[s2][nt]];
#pragma unroll
                for (int f = 0; f < 2; ++f) {
                    acc_a[f][nt] = __builtin_amdgcn_mfma_f32_16x16x32_bf16(af[0][f], bfr[1], acc_a[f][nt], 0, 0, 0);
                    acc_a[f][nt] = __builtin_amdgcn_mfma_f32_16x16x32_bf16(af[1][f], bfr[0], acc_a[f][nt], 0, 0, 0);
                    acc_a[f][nt] = __builtin_amdgcn_mfma_f32_16x16x32_bf16(af[0][f], bfr[0], acc_a[f][nt], 0, 0, 0);
                    acc_b[f][nt] = __builtin_amdgcn_mfma_f32_16x16x32_bf16(af[2][f], bfr[2], acc_b[f][nt], 0, 0, 0);
                }
            }
        }
        __syncthreads();
    }
}

// grid (HW/64, 1, N) — conv1: 256-o tile, plain GEMM + bias
__global__ __launch_bounds__(256, 3) void gemm_mfma_kernel(
    const unsigned short* __restrict__ X0, const unsigned short* __restrict__ X1,
    const unsigned short* __restrict__ X2, const unsigned short* __restrict__ W0,
    const unsigned short* __restrict__ W1, const unsigned short* __restrict__ W2,
    const float* __restrict__ bias, float* __restrict__ Y) {
    const int hw0 = blockIdx.x * 64, n = blockIdx.z;
    f32x4 acc[4][4] = {};
    mfma_core7(X0, X1, X2, W0, W1, W2, n, hw0, acc);
    const int lane = threadIdx.x & 63, wv = threadIdx.x >> 6;
    const int quad = lane >> 4, nlo = lane & 15;
#pragma unroll
    for (int f = 0; f < 4; ++f) {
        const int om = wv * 64 + f * 16 + quad * 4;
#pragma unroll
        for (int nt = 0; nt < 4; ++nt) {
            const int hw = hw0 + nt * 16 + nlo;
#pragma unroll
            for (int r = 0; r < 4; ++r) {
                const int o = om + r;
                Y[((size_t)(n * CC + o)) * HW + hw] = acc[f][nt][r] + bias[o];
            }
        }
    }
}

// conv2 GEMM (256-o tile) with fused XG formation + stats + conv4g dot.
// grid (HW/64, 1, N): one block covers all o for its hw tile -> s_pix is a
// plain store (no atomics needed).
__global__ __launch_bounds__(256, 3) void gemm_xg_kernel(
    const unsigned short* __restrict__ X0, const unsigned short* __restrict__ X1,
    const unsigned short* __restrict__ X2, const unsigned short* __restrict__ W0,
    const unsigned short* __restrict__ W1, const unsigned short* __restrict__ W2,
    const float* __restrict__ bias, const float* __restrict__ g1,
    const float* __restrict__ cgw,
    float* __restrict__ XG, float* __restrict__ sum_c, float* __restrict__ sq_c,
    float* __restrict__ s_pix) {
    const int hw0 = blockIdx.x * 64, n = blockIdx.z;
    f32x4 acc[4][4] = {};
    mfma_core7(X0, X1, X2, W0, W1, W2, n, hw0, acc);
    __shared__ float sRed[4][64];
    const int lane = threadIdx.x & 63, wv = threadIdx.x >> 6;
    const int quad = lane >> 4, nlo = lane & 15;
    float pnt[4] = {0.f, 0.f, 0.f, 0.f};
#pragma unroll
    for (int f = 0; f < 4; ++f) {
        const int om = wv * 64 + f * 16 + quad * 4;
#pragma unroll
        for (int r = 0; r < 4; ++r) {
            const int o = om + r;
            const float b = bias[o];
            const float wg = cgw[o];
            float s = 0.f, q = 0.f;
#pragma unroll
            for (int nt = 0; nt < 4; ++nt) {
                const int hw = hw0 + nt * 16 + nlo;
                const size_t rowi = ((size_t)(n * CC + o)) * HW + hw;
                const float xgv = acc[f][nt][r] + b + g1[rowi];
                XG[rowi] = xgv;
                s += xgv; q += xgv * xgv;
                pnt[nt] += wg * xgv;
            }
#pragma unroll
            for (int off = 1; off < 16; off <<= 1) { s += __shfl_xor(s, off); q += __shfl_xor(q, off); }
            if (nlo == 0) { atomicAdd(&sum_c[n * CC + o], s); atomicAdd(&sq_c[n * CC + o], q); }
        }
    }
#pragma unroll
    for (int nt = 0; nt < 4; ++nt) {
        float p = pnt[nt];
        p += __shfl_xor(p, 16); p += __shfl_xor(p, 32);
        if (quad == 0) sRed[wv][nt * 16 + nlo] = p;
    }
    __syncthreads();
    if (threadIdx.x < 64) {
        s_pix[n * HW + hw0 + threadIdx.x] = sRed[0][threadIdx.x] + sRed[1][threadIdx.x] +
                                            sRed[2][threadIdx.x] + sRed[3][threadIdx.x];
    }
}

// Merged conv4+conv3 GEMM with fused final-combine epilogue:
// xL = (conv3(dw)+b3)*gate + (conv4(x_up)+b4) + gui + XG*ca_sig  -> xL buffer
__global__ __launch_bounds__(256, 3) void gemm_final_kernel(
    const unsigned short* __restrict__ XUH, const unsigned short* __restrict__ XUL,
    const unsigned short* __restrict__ XDW,
    const unsigned short* __restrict__ W4H, const unsigned short* __restrict__ W4L,
    const unsigned short* __restrict__ W3B,
    const float* __restrict__ b3, const float* __restrict__ b4,
    const float* __restrict__ XG, const float* __restrict__ s_pix,
    const float* __restrict__ cgb,
    const float* __restrict__ gate, const float* __restrict__ ca_sig,
    const float* __restrict__ mu_g, const float* __restrict__ isd_g,
    const float* __restrict__ gamma, const float* __restrict__ beta,
    float* __restrict__ out) {
    const int hw0 = blockIdx.x * 64, o0 = blockIdx.y * 128, n = blockIdx.z;
    f32x4 acc_a[2][4] = {};
    f32x4 acc_b[2][4] = {};
    mfma_core_pair7(XUH, XUL, XDW, W4H, W4L, W3B, n, hw0, o0, acc_a, acc_b);
    const int lane = threadIdx.x & 63, wv = threadIdx.x >> 6;
    const int quad = lane >> 4, nlo = lane & 15;
    const float cgb0 = cgb[0];
#pragma unroll
    for (int f = 0; f < 2; ++f) {
        const int om = o0 + f * 64 + wv * 16 + quad * 4;
#pragma unroll
        for (int nt = 0; nt < 4; ++nt) {
            const int hw = hw0 + nt * 16 + nlo;
            const int pix = n * HW + hw;
            const float sp = sigmoidf_(s_pix[pix] + cgb0);
#pragma unroll
            for (int r = 0; r < 4; ++r) {
                const int o = om + r;
                const float g = gate[n * CC + o];
                const float cs = ca_sig[n * CC + o];
                const float mu = mu_g[n * 16 + (o >> 4)];
                const float isd = isd_g[n * 16 + (o >> 4)];
                const size_t rowi = ((size_t)(n * CC + o)) * HW + hw;
                const float xg = XG[rowi];
                const float gui = (sp * xg - mu) * isd * gamma[o] + beta[o];
                out[rowi] = (acc_b[f][nt][r] + b3[o]) * g + (acc_a[f][nt][r] + b4[o]) + gui + xg * cs;
            }
        }
    }
}

// grid N (16): rw=sigmoid(mean), ca conv1d(k=5,pad2)+sigmoid, group mu / 1/(sd+1e-10)
__global__ __launch_bounds__(256) void stats2_kernel(const float* __restrict__ sum_c,
                                                     const float* __restrict__ sq_c,
                                                     const float* __restrict__ caw,
                                                     float* __restrict__ rw,
                                                     float* __restrict__ ca_sig,
                                                     float* __restrict__ mu_g,
                                                     float* __restrict__ isd_g,
                                                     float* __restrict__ xlow_sum) {
    const int n = blockIdx.x, c = threadIdx.x;
    __shared__ float m[256];
    const float mean = sum_c[n * CC + c] * (1.f / (float)HW);
    m[c] = mean;
    rw[n * CC + c] = sigmoidf_(mean);
    xlow_sum[n * CC + c] = 0.f;
    __syncthreads();
    float y = 0.f;
#pragma unroll
    for (int k = 0; k < 5; ++k) {
        const int cc = c - 2 + k;
        if (cc >= 0 && cc < 256) y += m[cc] * caw[k];
    }
    ca_sig[n * CC + c] = sigmoidf_(y);
    if (c < 16) {
        float S = 0.f, Q = 0.f;
        for (int j = 0; j < 16; ++j) {
            S += sum_c[n * CC + c * 16 + j];
            Q += sq_c[n * CC + c * 16 + j];
        }
        const float cnt = 65536.f;
        const float mu = S / cnt;
        float var = (Q - S * S / cnt) * (1.f / (cnt - 1.f));
        var = fmaxf(var, 0.f);
        mu_g[n * 16 + c] = mu;
        isd_g[n * 16 + c] = 1.f / (sqrtf(var) + 1e-10f);
    }
}

// ---------------------------------------------------------------------------
// Fused masks + conv4-input transpose/split ([n][HW][C] layout).
// grid (HW/64, CC/64, N)
// ---------------------------------------------------------------------------
__global__ __launch_bounds__(256) void masks_split_kernel(
    float* g1_xlow,  // aliased in/out
    const float* __restrict__ XG,
    const float* __restrict__ rw,
    const float* __restrict__ bng, const float* __restrict__ bnb,
    const float* __restrict__ bnrm, const float* __restrict__ bnrv,
    unsigned short* __restrict__ O0, unsigned short* __restrict__ O1,
    float* __restrict__ xlow_sum) {
    const int hw0 = blockIdx.x * 64, c0 = blockIdx.y * 64, n = blockIdx.z;
    __shared__ float sT[64][65];
    const int tid = threadIdx.x;
    const int cl = tid >> 2;
    const int q = tid & 3;
    const int c = c0 + cl;
    const float inv = bng[c] / sqrtf(bnrv[c] + 1e-5f);
    const float off = bnb[c] - bnrm[c] * inv;
    const float rwv = rw[n * CC + c];
    const size_t rowb = ((size_t)(n * CC + c)) * HW + hw0;
    float lsum = 0.f;
#pragma unroll
    for (int j = 0; j < 4; ++j) {
        const int hwl = q * 4 + j * 16;
        const float4 a = *(const float4*)(g1_xlow + rowb + hwl);
        const float4 x = *(const float4*)(XG + rowb + hwl);
        const float* ap = &a.x; const float* xp = &x.x;
        float4 xlv;
        float* xlp = &xlv.x;
#pragma unroll
        for (int e = 0; e < 4; ++e) {
            const float g2e = xp[e] - ap[e];            // reconstruct g2
            const float w1 = sigmoidf_(inv * ap[e] + off);
            const float w2 = sigmoidf_(inv * g2e + off);
            const float cu = (rwv >= w1 ? 1.f : 0.f) + (rwv >= w2 ? 1.f : 0.f);
            const float xu = xp[e] * cu;
            const float xl = xp[e] * (2.f - cu);
            sT[cl][hwl + e] = xu;
            xlp[e] = xl;
            lsum += xl;
        }
        *(float4*)(g1_xlow + rowb + hwl) = xlv;
    }
    lsum += __shfl_xor(lsum, 1);
    lsum += __shfl_xor(lsum, 2);
    if (q == 0) atomicAdd(&xlow_sum[n * CC + c], lsum);
    __syncthreads();
    const int hwl2 = tid >> 2, cb = (tid & 3) << 4;
    unsigned short h[16], m[16];
#pragma unroll
    for (int j = 0; j < 16; ++j) {
        const float x = sT[cb + j][hwl2];
        const unsigned short hh = bf16_rne(x);
        h[j] = hh;
        m[j] = bf16_rne(x - bf16_tof(hh));
    }
    const size_t ob = ((size_t)(n * HW + hw0 + hwl2)) * 256 + c0 + cb;
    *(int4*)(O0 + ob) = *(int4*)&h[0]; *(int4*)(O0 + ob + 8) = *(int4*)&h[8];
    *(int4*)(O1 + ob) = *(int4*)&m[0]; *(int4*)(O1 + ob + 8) = *(int4*)&m[8];
}

// grid N: gate = softmax_c(relu(xlow_mean @ gate_w^T + gate_b))
__global__ __launch_bounds__(256) void gate_kernel(const float* __restrict__ xlow_sum,
                                                   const float* __restrict__ gatew,
                                                   const float* __restrict__ gateb,
                                                   float* __restrict__ gate) {
    const int n = blockIdx.x, c = threadIdx.x;
    __shared__ float xm[256];
    __shared__ float red[256];
    xm[c] = xlow_sum[n * CC + c] * (1.f / (float)HW);
    __syncthreads();
    float acc = gateb[c];
    const float* wr = gatew + (size_t)c * 256;
#pragma unroll 8
    for (int k = 0; k < 256; ++k) acc += xm[k] * wr[k];
    const float v = fmaxf(acc, 0.f);
    red[c] = v;
    __syncthreads();
    for (int s = 128; s > 0; s >>= 1) {
        if (c < s) red[c] = fmaxf(red[c], red[c + s]);
        __syncthreads();
    }
    const float mx = red[0];
    __syncthreads();
    const float e = expf(v - mx);
    red[c] = e;
    __syncthreads();
    for (int s = 128; s > 0; s >>= 1) {
        if (c < s) red[c] += red[c + s];
        __syncthreads();
    }
    gate[n * CC + c] = e / red[0];
}

// grid NC: depthwise 3x3 (pad 1) on x_low via LDS slab. IN-PLACE SAFE:
// the whole plane is staged to LDS before any write (block-local plane).
__global__ __launch_bounds__(256) void dwconv_kernel(const float* __restrict__ xlow,
                                                     const float* __restrict__ dww,
                                                     const float* __restrict__ dwb,
                                                     float* __restrict__ out) {
    const int c = blockIdx.x & 255;
    __shared__ float sl[64][65];
    const size_t base = (size_t)blockIdx.x * HW;
    for (int r = 0; r < 16; ++r) {
        const int idx = threadIdx.x + r * 256;
        sl[idx >> 6][idx & 63] = xlow[base + idx];
    }
    float wk[9];
#pragma unroll
    for (int j = 0; j < 9; ++j) wk[j] = dww[c * 9 + j];
    const float bias = dwb[c];
    __syncthreads();
    for (int r = 0; r < 16; ++r) {
        const int idx = threadIdx.x + r * 256;
        const int h = idx >> 6, w = idx & 63;
        float acc = bias;
#pragma unroll
        for (int dh = 0; dh < 3; ++dh) {
            const int hh = h + dh - 1;
            if (hh < 0 || hh > 63) continue;
#pragma unroll
            for (int dw2 = 0; dw2 < 3; ++dw2) {
                const int ww2 = w + dw2 - 1;
                if (ww2 < 0 || ww2 > 63) continue;
                acc += sl[hh][ww2] * wk[dh * 3 + dw2];
            }
        }
        out[base + idx] = acc;
    }
}

// grid NC: xh[n,c,h]=mean_w xL, xw[n,c,w]=mean_h xL
__global__ __launch_bounds__(256) void pool_kernel(const float* __restrict__ xL,
                                                   float* __restrict__ xh,
                                                   float* __restrict__ xw) {
    __shared__ float sl[64][65];
    const size_t base = (size_t)blockIdx.x * HW;
    for (int r = 0; r < 16; ++r) {
        const int idx = threadIdx.x + r * 256;
        sl[idx >> 6][idx & 63] = xL[base + idx];
    }
    __syncthreads();
    const int t = threadIdx.x;
    if (t < 64) {
        float s = 0.f;
        for (int w = 0; w < 64; ++w) s += sl[t][w];
        xh[(size_t)blockIdx.x * 64 + t] = s * (1.f / 64.f);
    } else if (t < 128) {
        const int w = t - 64;
        float s = 0.f;
        for (int h = 0; h < 64; ++h) s += sl[h][w];
        xw[(size_t)blockIdx.x * 64 + w] = s * (1.f / 64.f);
    }
}

// grid N: yc = relu(bn(la1 @ [xh;xw])); sh = sig(fh@yc_h), sw = sig(fw@yc_w)
__global__ __launch_bounds__(256) void local_att_kernel(const float* __restrict__ xh,
                                                        const float* __restrict__ xw,
                                                        const float* __restrict__ la1w,
                                                        const float* __restrict__ lag,
                                                        const float* __restrict__ lab,
                                                        const float* __restrict__ larm,
                                                        const float* __restrict__ larv,
                                                        const float* __restrict__ fhw,
                                                        const float* __restrict__ fww,
                                                        float* __restrict__ sh,
                                                        float* __restrict__ sw) {
    const int n = blockIdx.x;
    __shared__ float w1s[16 * 256];
    __shared__ float fhs[256 * 16];
    __shared__ float fws[256 * 16];
    __shared__ float ycs[16][128];
    for (int i = threadIdx.x; i < 4096; i += 256) {
        w1s[i] = la1w[i];
        fhs[i] = fhw[i];
        fws[i] = fww[i];
    }
    __syncthreads();
    for (int idx = threadIdx.x; idx < 2048; idx += 256) {
        const int m = idx >> 7, p = idx & 127;
        const float* vsrc = (p < 64) ? (xh + (size_t)n * CC * 64 + p)
                                     : (xw + (size_t)n * CC * 64 + (p - 64));
        float acc = 0.f;
#pragma unroll 8
        for (int c = 0; c < 256; ++c) acc += w1s[m * 256 + c] * vsrc[(size_t)c * 64];
        const float inv = lag[m] / sqrtf(larv[m] + 1e-5f);
        const float off = lab[m] - larm[m] * inv;
        ycs[m][p] = fmaxf(inv * acc + off, 0.f);
    }
    __syncthreads();
    for (int idx = threadIdx.x; idx < 16384; idx += 256) {
        const int c = idx >> 6, h = idx & 63;
        float a1 = 0.f, a2 = 0.f;
#pragma unroll
        for (int m = 0; m < 16; ++m) {
            a1 += fhs[c * 16 + m] * ycs[m][h];
            a2 += fws[c * 16 + m] * ycs[m][64 + h];
        }
        sh[(size_t)n * CC * 64 + idx] = sigmoidf_(a1);
        sw[(size_t)n * CC * 64 + idx] = sigmoidf_(a2);
    }
}

// grid NC: out = xL * sh[h]*sw[w]  (out-of-place: xL in workspace, out = d_out)
__global__ __launch_bounds__(256) void final_kernel(const float* __restrict__ xL,
                                                    const float* __restrict__ sh,
                                                    const float* __restrict__ sw,
                                                    float* __restrict__ out) {
    __shared__ float shs[64], sws[64];
    const int t = threadIdx.x;
    if (t < 64) shs[t] = sh[(size_t)blockIdx.x * 64 + t];
    else if (t < 128) sws[t - 64] = sw[(size_t)blockIdx.x * 64 + (t - 64)];
    __syncthreads();
    const size_t base = (size_t)blockIdx.x * HW;
#pragma unroll 4
    for (int r = 0; r < 16; ++r) {
        const int idx = t + r * 256;
        out[base + idx] = xL[base + idx] * shs[idx >> 6] * sws[idx & 63];
    }
}

extern "C" void kernel_launch(void* const* d_in, const int* in_sizes, int n_in,
                              void* d_out, int out_size, void* d_ws, size_t ws_size,
                              hipStream_t stream) {
    const float* x1 = (const float*)d_in[0];
    const float* x2 = (const float*)d_in[1];
    const float* c1w = (const float*)d_in[2];
    const float* c1b = (const float*)d_in[3];
    const float* c2w = (const float*)d_in[4];
    const float* c2b = (const float*)d_in[5];
    const float* c3w = (const float*)d_in[6];
    const float* c3b = (const float*)d_in[7];
    const float* c4w = (const float*)d_in[8];
    const float* c4b = (const float*)d_in[9];
    const float* cgw = (const float*)d_in[10];
    const float* cgb = (const float*)d_in[11];
    const float* bng = (const float*)d_in[12];
    const float* bnb = (const float*)d_in[13];
    const float* bnrm = (const float*)d_in[14];
    const float* bnrv = (const float*)d_in[15];
    const float* gamma = (const float*)d_in[16];
    const float* beta = (const float*)d_in[17];
    const float* gatew = (const float*)d_in[18];
    const float* gateb = (const float*)d_in[19];
    const float* dww = (const float*)d_in[20];
    const float* dwb = (const float*)d_in[21];
    // d_in[22], d_in[23]: interact_w/b — dead code (softmax over size-1 axis == 1)
    const float* caw = (const float*)d_in[24];
    const float* la1w = (const float*)d_in[25];
    const float* lag = (const float*)d_in[26];
    const float* lab = (const float*)d_in[27];
    const float* larm = (const float*)d_in[28];
    const float* larv = (const float*)d_in[29];
    const float* fhw = (const float*)d_in[30];
    const float* fww = (const float*)d_in[31];

    // ---- Workspace plan (A eliminated; merged conv4+conv3 GEMM) ----
    // buf0: g1 -> x_low -> dw (in place) -> xL (merged-gemm output)
    // buf1: [conv1 splits hi,mid] -> XG (alive through gemm_final)
    // buf2: [conv1/conv2 lo split] -> dw split (1 FSZ us)
    // d_out: [conv2 splits hi,mid] -> [x_up splits hi,lo] -> final out
    float* ws = (float*)d_ws;
    float* buf0 = ws;
    float* buf1 = ws + FSZ;
    float* buf2 = ws + 2 * FSZ;
    float* sp = ws + 3 * FSZ;
    float* sum_c = sp;    sp += 4096;   // later reused as gate
    float* sq_c = sp;     sp += 4096;   // contiguous with sum_c (zeroed together)
    float* rw = sp;       sp += 4096;
    float* ca_sig = sp;   sp += 4096;
    float* xlow_sum = sp; sp += 4096;
    float* mu_g = sp;     sp += 256;
    float* isd_g = sp;    sp += 256;
    float* s_pix = sp;    sp += (size_t)NN * HW;       // 65536, raw (pre-sigmoid)
    float* xh = sp;       sp += (size_t)NN * CC * 64;  // 262144
    float* xwb = sp;      sp += (size_t)NN * CC * 64;
    float* shb = sp;      sp += (size_t)NN * CC * 64;
    float* swb = sp;      sp += (size_t)NN * CC * 64;
    // weight splits overlap shb/swb (written only at step 10; weights dead by then)
    unsigned short* wsp = (unsigned short*)shb;
    unsigned short* w1h = wsp + 0 * 65536;
    unsigned short* w1m = wsp + 1 * 65536;
    unsigned short* w1l = wsp + 2 * 65536;
    unsigned short* w2h = wsp + 3 * 65536;
    unsigned short* w2m = wsp + 4 * 65536;
    unsigned short* w2l = wsp + 5 * 65536;
    unsigned short* w4h = wsp + 6 * 65536;
    unsigned short* w4l = wsp + 7 * 65536;
    unsigned short* w3b = wsp + 8 * 65536;

    float* out = (float*)d_out;

    const dim3 gt(HW / 64, CC / 64, NN);   // tsplit/masks grids (64, 4, 16)
    const dim3 g1g(HW / 64, 1, NN);        // 256-o gemm grids (64, 1, 16)
    const dim3 g2g(HW / 64, CC / 128, NN); // pair gemm grid (64, 2, 16)

    // 0: weight splits (fragment order) + zero sum_c/sq_c and s_pix accumulators
    wsplit_kernel<<<256, 256, 0, stream>>>(c1w, c2w, c3w, c4w, w1h, w1m, w1l,
                                           w2h, w2m, w2l, w4h, w4l, w3b,
                                           sum_c, s_pix);
    // 1: g1 = conv1(x1)  (3-split ~fp32 MFMA). Splits: buf1 (hi,mid) + buf2 (lo).
    {
        unsigned short* sx0 = (unsigned short*)buf1;
        unsigned short* sx1 = (unsigned short*)buf1 + FSZ;
        unsigned short* sx2 = (unsigned short*)buf2;
        tsplit_kernel<3><<<gt, 256, 0, stream>>>(x1, sx0, sx1, sx2);
        gemm_mfma_kernel<<<g1g, 256, 0, stream>>>(sx0, sx1, sx2, w1h, w1m, w1l, c1b, buf0);
    }
    // 2: XG = conv2(x2) + g1 fused. Splits: d_out (hi,mid) + buf2 (lo).
    //    Epilogue also accumulates sum_c/sq_c (XG stats) and stores s_pix.
    {
        unsigned short* sx0 = (unsigned short*)out;
        unsigned short* sx1 = (unsigned short*)out + FSZ;
        unsigned short* sx2 = (unsigned short*)buf2;
        tsplit_kernel<3><<<gt, 256, 0, stream>>>(x2, sx0, sx1, sx2);
        gemm_xg_kernel<<<g1g, 256, 0, stream>>>(sx0, sx1, sx2, w2h, w2m, w2l, c2b,
                                                buf0, cgw, buf1, sum_c, sq_c, s_pix);
    }
    // 3: rw, channel-att sigmoid, group mu/invsd (+ zero xlow_sum)
    stats2_kernel<<<NN, 256, 0, stream>>>(sum_c, sq_c, caw, rw, ca_sig, mu_g, isd_g, xlow_sum);
    // 4: fused masks + conv4-input split (g2 = XG - g1): x_low -> buf0 (in place),
    //    x_up splits -> d_out, xlow_sum via atomics (zeroed in step 3)
    {
        unsigned short* ux0 = (unsigned short*)out;
        unsigned short* ux1 = (unsigned short*)out + FSZ;
        masks_split_kernel<<<gt, 256, 0, stream>>>(buf0, buf1, rw, bng, bnb, bnrm, bnrv,
                                                   ux0, ux1, xlow_sum);
    }
    // 5: gate softmax (output reuses sum_c)
    float* gate = sum_c;
    gate_kernel<<<NN, 256, 0, stream>>>(xlow_sum, gatew, gateb, gate);
    // 6: dwconv on x_low -> buf0 IN PLACE (plane staged to LDS before writes)
    dwconv_kernel<<<NN * CC, 256, 0, stream>>>(buf0, dww, dwb, buf0);
    // 7: conv3 input split: dw(buf0) -> buf2 ushorts
    {
        unsigned short* sx0 = (unsigned short*)buf2;
        tsplit_kernel<1><<<gt, 256, 0, stream>>>(buf0, sx0, nullptr, nullptr);
    }
    // 8: merged conv4+conv3 GEMM + final combine -> xL in buf0 (dw fp32 dead).
    //    Reads x_up splits (d_out), dw split (buf2), XG (buf1).
    {
        unsigned short* ux0 = (unsigned short*)out;
        unsigned short* ux1 = (unsigned short*)out + FSZ;
        unsigned short* sx0 = (unsigned short*)buf2;
        gemm_final_kernel<<<g2g, 256, 0, stream>>>(ux0, ux1, sx0, w4h, w4l, w3b,
                                                   c3b, c4b, buf1, s_pix, cgb,
                                                   gate, ca_sig, mu_g, isd_g, gamma, beta,
                                                   buf0);
    }
    // 9: pools (read xL from buf0)
    pool_kernel<<<NN * CC, 256, 0, stream>>>(buf0, xh, xwb);
    // 10: coordinate attention -> sh, sw (overwrites weight-split region — weights dead)
    local_att_kernel<<<NN, 256, 0, stream>>>(xh, xwb, la1w, lag, lab, larm, larv,
                                             fhw, fww, shb, swb);
    // 11: out = xL * sh*sw  (buf0 -> d_out; x_up splits in d_out are dead)
    final_kernel<<<NN * CC, 256, 0, stream>>>(buf0, shb, swb, out);
}

// Round 8
// 637.595 us; speedup vs baseline: 1.0782x; 1.0782x over previous
//
#include <hip/hip_runtime.h>
#include <cstddef>
#include <cstdint>

// Problem constants (fixed by reference setup_inputs)
constexpr int NN = 16, CC = 256, HH = 64, WW = 64, HW = 64 * 64; // 4096
constexpr size_t FSZ = (size_t)NN * CC * HW;                      // 16,777,216

typedef short bf16x8 __attribute__((ext_vector_type(8)));
typedef float f32x4 __attribute__((ext_vector_type(4)));

__device__ __forceinline__ float sigmoidf_(float x) { return 1.f / (1.f + expf(-x)); }

__device__ __forceinline__ unsigned short bf16_rne(float f) {
    uint32_t u = __builtin_bit_cast(uint32_t, f);
    u += 0x7FFFu + ((u >> 16) & 1u);
    return (unsigned short)(u >> 16);
}
__device__ __forceinline__ float bf16_tof(unsigned short h) {
    uint32_t u = ((uint32_t)h) << 16;
    return __builtin_bit_cast(float, u);
}

// Direct global->LDS DMA, 16B per lane. LDS dest = wave-uniform base + lane*16.
__device__ __forceinline__ void gload16(const void* g, void* l) {
    __builtin_amdgcn_global_load_lds((const __attribute__((address_space(1))) void*)g,
                                     (__attribute__((address_space(3))) void*)l, 16, 0, 0);
}

// ---------------------------------------------------------------------------
// W fragment-order layout (A-operand), logical (o, k) of a 256x256 matrix:
//   elem = ((o>>4)*8 + (k>>5))*512 + ((k&31)>>3)*128 + (o&15)*8 + (k&7)
// A wave reads one 16(o)x32(k) fragment as base + lane*8 ushorts (R3-verified).
//
// GEMM cores are the R6-verified structure (645 us, SQ_LDS_BANK_CONFLICT=0):
// X staged via global_load_lds into double-buffered LINEAR LDS [64][32]us;
// 16B chunks XOR-permuted within each 64B row (slot = chunk^((row>>1)&3)) via
// PRE-SWIZZLED global source (LDS writes stay linear), consumed by swizzled
// ds_read slot quad^((row>>1)&3). W fragments global->register, double-
// buffered one k-step ahead. BK=32, o-tile 128, 4 waves. (R7's BK=64/256-o
// variant regressed: L2 thrash, FETCH+WRITE +50MB.)
// ---------------------------------------------------------------------------

// ---------------------------------------------------------------------------
// Weight split -> fragment order. Also zeroes sum_c/sq_c and s_pix.
// ---------------------------------------------------------------------------
__global__ __launch_bounds__(256) void wsplit_kernel(
    const float* __restrict__ w1, const float* __restrict__ w2,
    const float* __restrict__ w3, const float* __restrict__ w4,
    unsigned short* __restrict__ w1h, unsigned short* __restrict__ w1m, unsigned short* __restrict__ w1l,
    unsigned short* __restrict__ w2h, unsigned short* __restrict__ w2m, unsigned short* __restrict__ w2l,
    unsigned short* __restrict__ w4h, unsigned short* __restrict__ w4l,
    unsigned short* __restrict__ w3b,
    float* __restrict__ zstat, float* __restrict__ zspix) {
    const int i = blockIdx.x * 256 + threadIdx.x;  // 65536 weights each
    const int o = i >> 8, c = i & 255;
    const size_t fo = ((size_t)((o >> 4) * 8 + (c >> 5))) * 512 +
                      (size_t)(((c & 31) >> 3) * 128 + (o & 15) * 8 + (c & 7));
    {
        float x = w1[i];
        unsigned short h = bf16_rne(x); float r = x - bf16_tof(h);
        unsigned short m = bf16_rne(r); float r2 = r - bf16_tof(m);
        w1h[fo] = h; w1m[fo] = m; w1l[fo] = bf16_rne(r2);
    }
    {
        float x = w2[i];
        unsigned short h = bf16_rne(x); float r = x - bf16_tof(h);
        unsigned short m = bf16_rne(r); float r2 = r - bf16_tof(m);
        w2h[fo] = h; w2m[fo] = m; w2l[fo] = bf16_rne(r2);
    }
    {
        float x = w4[i];
        unsigned short h = bf16_rne(x); float r = x - bf16_tof(h);
        w4h[fo] = h; w4l[fo] = bf16_rne(r);
    }
    w3b[fo] = bf16_rne(w3[i]);
    if (i < 8192) zstat[i] = 0.f;   // sum_c (4096) + sq_c (4096), contiguous
    zspix[i] = 0.f;                 // s_pix raw accumulator (NN*HW = 65536)
}

// ---------------------------------------------------------------------------
// Transpose + split: X fp32 [n][C][HW] -> 3 bf16 arrays [n][HW][C]
// grid (HW/64, C/64, N), 256 threads
// ---------------------------------------------------------------------------
__global__ __launch_bounds__(256) void tsplit3_kernel(const float* __restrict__ X,
                                                      unsigned short* __restrict__ O0,
                                                      unsigned short* __restrict__ O1,
                                                      unsigned short* __restrict__ O2) {
    const int hw0 = blockIdx.x * 64, c0 = blockIdx.y * 64, n = blockIdx.z;
    __shared__ float sT[64][65];
    const int tid = threadIdx.x;
    {
        const int hwl = (tid & 15) << 2;
        const int cl = tid >> 4;  // 0..15
#pragma unroll
        for (int p = 0; p < 4; ++p) {
            const int c = cl + p * 16;
            const float4 v = *(const float4*)(X + ((size_t)(n * CC + c0 + c)) * HW + hw0 + hwl);
            sT[c][hwl] = v.x; sT[c][hwl + 1] = v.y; sT[c][hwl + 2] = v.z; sT[c][hwl + 3] = v.w;
        }
    }
    __syncthreads();
    const int hwl = tid >> 2, cb = (tid & 3) << 4;
    unsigned short h[16], m[16], l[16];
#pragma unroll
    for (int j = 0; j < 16; ++j) {
        const float x = sT[cb + j][hwl];
        const unsigned short hh = bf16_rne(x);
        h[j] = hh;
        const float r = x - bf16_tof(hh);
        const unsigned short mm = bf16_rne(r);
        m[j] = mm;
        l[j] = bf16_rne(r - bf16_tof(mm));
    }
    const size_t ob = ((size_t)(n * HW + hw0 + hwl)) * 256 + c0 + cb;
    *(int4*)(O0 + ob) = *(int4*)&h[0]; *(int4*)(O0 + ob + 8) = *(int4*)&h[8];
    *(int4*)(O1 + ob) = *(int4*)&m[0]; *(int4*)(O1 + ob + 8) = *(int4*)&m[8];
    *(int4*)(O2 + ob) = *(int4*)&l[0]; *(int4*)(O2 + ob + 8) = *(int4*)&l[8];
}

// ---------------------------------------------------------------------------
// Transpose (bf16 in, bf16 out): X ushort [n][C][HW] -> [n][HW][C]
// grid (HW/64, C/64, N). Used for the dw -> conv3 input path.
// ---------------------------------------------------------------------------
__global__ __launch_bounds__(256) void tsplit_bf16_kernel(const unsigned short* __restrict__ X,
                                                          unsigned short* __restrict__ O0) {
    const int hw0 = blockIdx.x * 64, c0 = blockIdx.y * 64, n = blockIdx.z;
    __shared__ unsigned short sT[64][72];   // pad 72 us (144B rows)
    const int tid = threadIdx.x;
    {
        const int cl = tid >> 3;            // 0..31
        const int ch = (tid & 7) * 8;       // 8-us chunk
#pragma unroll
        for (int p = 0; p < 2; ++p) {
            const int c = cl + p * 32;
            const int4 v = *(const int4*)(X + ((size_t)(n * CC + c0 + c)) * HW + hw0 + ch);
            *(int4*)&sT[c][ch] = v;
        }
    }
    __syncthreads();
    const int hwl = tid >> 2, cb = (tid & 3) << 4;
    unsigned short h[16];
#pragma unroll
    for (int j = 0; j < 16; ++j) h[j] = sT[cb + j][hwl];
    const size_t ob = ((size_t)(n * HW + hw0 + hwl)) * 256 + c0 + cb;
    *(int4*)(O0 + ob) = *(int4*)&h[0]; *(int4*)(O0 + ob + 8) = *(int4*)&h[8];
}

// ---------------------------------------------------------------------------
// MFMA GEMM core v6 (R6-verified): X via global_load_lds into double-buffered
// linear LDS with XOR-swizzled chunks; W global->register one k-step ahead.
// Tile 128(o) x 64(hw), K=256 in steps of 32, 4 waves.
// acc[f][nt]: o = o0 + f*64 + wv*16 + quad*4 + reg, hw = hw0 + nt*16 + (lane&15)
// ---------------------------------------------------------------------------
template <int NS>
__device__ __forceinline__ void mfma_core6(const unsigned short* __restrict__ X0,
                                           const unsigned short* __restrict__ X1,
                                           const unsigned short* __restrict__ X2,
                                           const unsigned short* __restrict__ W0,
                                           const unsigned short* __restrict__ W1,
                                           const unsigned short* __restrict__ W2,
                                           int n, int hw0, int o0, f32x4 (&acc)[2][4]) {
    __shared__ unsigned short sX[2][NS][64][32];   // linear, 4KB per (buf,s)
    const int tid = threadIdx.x;
    const int lane = tid & 63, wv = tid >> 6, quad = lane >> 4, nlo = lane & 15;
    const int srow = tid >> 2;                          // staging row 0..63
    const int schunk = (tid & 3) ^ ((srow >> 1) & 3);   // pre-swizzled source chunk
    const unsigned short* Xs[3] = {X0, X1, X2};
    const unsigned short* Ws[3] = {W0, W1, W2};
    const size_t xg = ((size_t)(n * HW + hw0 + srow)) * 256 + schunk * 8;
    const unsigned short* wp[NS];
#pragma unroll
    for (int s = 0; s < NS; ++s)
        wp[s] = Ws[s] + ((size_t)((o0 >> 4) + wv) * 8) * 512 + (size_t)lane * 8;

    // swizzled LDS read offsets (ushort index within one [64][32] tile)
    int roff[4];
#pragma unroll
    for (int nt = 0; nt < 4; ++nt) {
        const int rrow = nt * 16 + nlo;
        roff[nt] = rrow * 32 + (quad ^ ((rrow >> 1) & 3)) * 8;
    }

    bf16x8 af[2][NS][2];
    // prologue: async-stage k-step 0 into buffer 0; prefetch W k0 into af[0]
#pragma unroll
    for (int s = 0; s < NS; ++s)
        gload16(Xs[s] + xg, &sX[0][s][wv * 16][0]);
#pragma unroll
    for (int s = 0; s < NS; ++s)
#pragma unroll
        for (int f = 0; f < 2; ++f)
            af[0][s][f] = *(const bf16x8*)(wp[s] + ((size_t)(f * 32)) * 512);
    __syncthreads();

#pragma unroll
    for (int ks = 0; ks < 8; ++ks) {
        const int cur = ks & 1;
        if (ks < 7) {
            // issue next k-step's X DMA + W register prefetch; the barrier at
            // the end of this iteration drains them (latency hidden by MFMAs)
#pragma unroll
            for (int s = 0; s < NS; ++s)
                gload16(Xs[s] + xg + (ks + 1) * 32, &sX[cur ^ 1][s][wv * 16][0]);
#pragma unroll
            for (int s = 0; s < NS; ++s)
#pragma unroll
                for (int f = 0; f < 2; ++f)
                    af[cur ^ 1][s][f] = *(const bf16x8*)(wp[s] + ((size_t)(f * 32 + ks + 1)) * 512);
        }
#pragma unroll
        for (int nt = 0; nt < 4; ++nt) {
            bf16x8 bfr[NS];
#pragma unroll
            for (int s = 0; s < NS; ++s)
                bfr[s] = *(const bf16x8*)&sX[cur][s][0][roff[nt]];
#pragma unroll
            for (int f = 0; f < 2; ++f) {
                if (NS == 3) {
                    acc[f][nt] = __builtin_amdgcn_mfma_f32_16x16x32_bf16(af[cur][1][f], bfr[1], acc[f][nt], 0, 0, 0);
                    acc[f][nt] = __builtin_amdgcn_mfma_f32_16x16x32_bf16(af[cur][0][f], bfr[2], acc[f][nt], 0, 0, 0);
                    acc[f][nt] = __builtin_amdgcn_mfma_f32_16x16x32_bf16(af[cur][2][f], bfr[0], acc[f][nt], 0, 0, 0);
                    acc[f][nt] = __builtin_amdgcn_mfma_f32_16x16x32_bf16(af[cur][0][f], bfr[1], acc[f][nt], 0, 0, 0);
                    acc[f][nt] = __builtin_amdgcn_mfma_f32_16x16x32_bf16(af[cur][1][f], bfr[0], acc[f][nt], 0, 0, 0);
                    acc[f][nt] = __builtin_amdgcn_mfma_f32_16x16x32_bf16(af[cur][0][f], bfr[0], acc[f][nt], 0, 0, 0);
                } else if (NS == 2) {
                    acc[f][nt] = __builtin_amdgcn_mfma_f32_16x16x32_bf16(af[cur][0][f], bfr[1], acc[f][nt], 0, 0, 0);
                    acc[f][nt] = __builtin_amdgcn_mfma_f32_16x16x32_bf16(af[cur][1][f], bfr[0], acc[f][nt], 0, 0, 0);
                    acc[f][nt] = __builtin_amdgcn_mfma_f32_16x16x32_bf16(af[cur][0][f], bfr[0], acc[f][nt], 0, 0, 0);
                } else {
                    acc[f][nt] = __builtin_amdgcn_mfma_f32_16x16x32_bf16(af[cur][0][f], bfr[0], acc[f][nt], 0, 0, 0);
                }
            }
        }
        __syncthreads();
    }
}

// ---------------------------------------------------------------------------
// Paired-product core (merged conv4+conv3), same v6 staging. acc_a gets
// conv4's 3 split-products, acc_b conv3's single product (32 MFMA/k-step).
// ---------------------------------------------------------------------------
__device__ __forceinline__ void mfma_core_pair(const unsigned short* __restrict__ XUH,
                                               const unsigned short* __restrict__ XUL,
                                               const unsigned short* __restrict__ XDW,
                                               const unsigned short* __restrict__ W4H,
                                               const unsigned short* __restrict__ W4L,
                                               const unsigned short* __restrict__ W3B,
                                               int n, int hw0, int o0,
                                               f32x4 (&acc_a)[2][4], f32x4 (&acc_b)[2][4]) {
    __shared__ unsigned short sX[2][3][64][32];
    const int tid = threadIdx.x;
    const int lane = tid & 63, wv = tid >> 6, quad = lane >> 4, nlo = lane & 15;
    const int srow = tid >> 2;
    const int schunk = (tid & 3) ^ ((srow >> 1) & 3);
    const unsigned short* Xs[3] = {XUH, XUL, XDW};
    const unsigned short* Ws[3] = {W4H, W4L, W3B};
    const size_t xg = ((size_t)(n * HW + hw0 + srow)) * 256 + schunk * 8;
    const unsigned short* wp[3];
#pragma unroll
    for (int s = 0; s < 3; ++s)
        wp[s] = Ws[s] + ((size_t)((o0 >> 4) + wv) * 8) * 512 + (size_t)lane * 8;

    int roff[4];
#pragma unroll
    for (int nt = 0; nt < 4; ++nt) {
        const int rrow = nt * 16 + nlo;
        roff[nt] = rrow * 32 + (quad ^ ((rrow >> 1) & 3)) * 8;
    }

    bf16x8 af[2][3][2];
#pragma unroll
    for (int s = 0; s < 3; ++s)
        gload16(Xs[s] + xg, &sX[0][s][wv * 16][0]);
#pragma unroll
    for (int s = 0; s < 3; ++s)
#pragma unroll
        for (int f = 0; f < 2; ++f)
            af[0][s][f] = *(const bf16x8*)(wp[s] + ((size_t)(f * 32)) * 512);
    __syncthreads();

#pragma unroll
    for (int ks = 0; ks < 8; ++ks) {
        const int cur = ks & 1;
        if (ks < 7) {
#pragma unroll
            for (int s = 0; s < 3; ++s)
                gload16(Xs[s] + xg + (ks + 1) * 32, &sX[cur ^ 1][s][wv * 16][0]);
#pragma unroll
            for (int s = 0; s < 3; ++s)
#pragma unroll
                for (int f = 0; f < 2; ++f)
                    af[cur ^ 1][s][f] = *(const bf16x8*)(wp[s] + ((size_t)(f * 32 + ks + 1)) * 512);
        }
#pragma unroll
        for (int nt = 0; nt < 4; ++nt) {
            bf16x8 bfr[3];
#pragma unroll
            for (int s = 0; s < 3; ++s)
                bfr[s] = *(const bf16x8*)&sX[cur][s][0][roff[nt]];
#pragma unroll
            for (int f = 0; f < 2; ++f) {
                // conv4 (2-split cross, same order as old NS=2 kernel)
                acc_a[f][nt] = __builtin_amdgcn_mfma_f32_16x16x32_bf16(af[cur][0][f], bfr[1], acc_a[f][nt], 0, 0, 0);
                acc_a[f][nt] = __builtin_amdgcn_mfma_f32_16x16x32_bf16(af[cur][1][f], bfr[0], acc_a[f][nt], 0, 0, 0);
                acc_a[f][nt] = __builtin_amdgcn_mfma_f32_16x16x32_bf16(af[cur][0][f], bfr[0], acc_a[f][nt], 0, 0, 0);
                // conv3 (plain bf16)
                acc_b[f][nt] = __builtin_amdgcn_mfma_f32_16x16x32_bf16(af[cur][2][f], bfr[2], acc_b[f][nt], 0, 0, 0);
            }
        }
        __syncthreads();
    }
}

// grid (HW/64, CC/128, N) — plain GEMM + bias (used for conv1 g1)
template <int NS>
__global__ __launch_bounds__(256, 3) void gemm_mfma_kernel(
    const unsigned short* __restrict__ X0, const unsigned short* __restrict__ X1,
    const unsigned short* __restrict__ X2, const unsigned short* __restrict__ W0,
    const unsigned short* __restrict__ W1, const unsigned short* __restrict__ W2,
    const float* __restrict__ bias, float* __restrict__ Y) {
    const int hw0 = blockIdx.x * 64, o0 = blockIdx.y * 128, n = blockIdx.z;
    f32x4 acc[2][4] = {};
    mfma_core6<NS>(X0, X1, X2, W0, W1, W2, n, hw0, o0, acc);
    const int lane = threadIdx.x & 63, wv = threadIdx.x >> 6;
    const int quad = lane >> 4, nlo = lane & 15;
#pragma unroll
    for (int f = 0; f < 2; ++f) {
        const int om = o0 + f * 64 + wv * 16 + quad * 4;
#pragma unroll
        for (int nt = 0; nt < 4; ++nt) {
            const int hw = hw0 + nt * 16 + nlo;
#pragma unroll
            for (int r = 0; r < 4; ++r) {
                const int o = om + r;
                Y[((size_t)(n * CC + o)) * HW + hw] = acc[f][nt][r] + bias[o];
            }
        }
    }
}

// conv2 GEMM with fused XG formation + stats + conv4g partial dot.
__global__ __launch_bounds__(256, 3) void gemm_xg_kernel(
    const unsigned short* __restrict__ X0, const unsigned short* __restrict__ X1,
    const unsigned short* __restrict__ X2, const unsigned short* __restrict__ W0,
    const unsigned short* __restrict__ W1, const unsigned short* __restrict__ W2,
    const float* __restrict__ bias, const float* __restrict__ g1,
    const float* __restrict__ cgw,
    float* __restrict__ XG, float* __restrict__ sum_c, float* __restrict__ sq_c,
    float* __restrict__ s_pix) {
    const int hw0 = blockIdx.x * 64, o0 = blockIdx.y * 128, n = blockIdx.z;
    f32x4 acc[2][4] = {};
    mfma_core6<3>(X0, X1, X2, W0, W1, W2, n, hw0, o0, acc);
    __shared__ float sRed[4][64];
    const int lane = threadIdx.x & 63, wv = threadIdx.x >> 6;
    const int quad = lane >> 4, nlo = lane & 15;
    float pnt[4] = {0.f, 0.f, 0.f, 0.f};
#pragma unroll
    for (int f = 0; f < 2; ++f) {
        const int om = o0 + f * 64 + wv * 16 + quad * 4;
#pragma unroll
        for (int r = 0; r < 4; ++r) {
            const int o = om + r;
            const float b = bias[o];
            const float wg = cgw[o];
            float s = 0.f, q = 0.f;
#pragma unroll
            for (int nt = 0; nt < 4; ++nt) {
                const int hw = hw0 + nt * 16 + nlo;
                const size_t rowi = ((size_t)(n * CC + o)) * HW + hw;
                const float xgv = acc[f][nt][r] + b + g1[rowi];
                XG[rowi] = xgv;
                s += xgv; q += xgv * xgv;
                pnt[nt] += wg * xgv;
            }
#pragma unroll
            for (int off = 1; off < 16; off <<= 1) { s += __shfl_xor(s, off); q += __shfl_xor(q, off); }
            if (nlo == 0) { atomicAdd(&sum_c[n * CC + o], s); atomicAdd(&sq_c[n * CC + o], q); }
        }
    }
#pragma unroll
    for (int nt = 0; nt < 4; ++nt) {
        float p = pnt[nt];
        p += __shfl_xor(p, 16); p += __shfl_xor(p, 32);
        if (quad == 0) sRed[wv][nt * 16 + nlo] = p;
    }
    __syncthreads();
    if (threadIdx.x < 64) {
        const float s2 = sRed[0][threadIdx.x] + sRed[1][threadIdx.x] +
                         sRed[2][threadIdx.x] + sRed[3][threadIdx.x];
        atomicAdd(&s_pix[n * HW + hw0 + threadIdx.x], s2);
    }
}

// Merged conv4+conv3 GEMM with fused final-combine epilogue:
// xL = (conv3(dw)+b3)*gate + (conv4(x_up)+b4) + gui + XG*ca_sig  -> xL buffer
__global__ __launch_bounds__(256, 3) void gemm_final_kernel(
    const unsigned short* __restrict__ XUH, const unsigned short* __restrict__ XUL,
    const unsigned short* __restrict__ XDW,
    const unsigned short* __restrict__ W4H, const unsigned short* __restrict__ W4L,
    const unsigned short* __restrict__ W3B,
    const float* __restrict__ b3, const float* __restrict__ b4,
    const float* __restrict__ XG, const float* __restrict__ s_pix,
    const float* __restrict__ cgb,
    const float* __restrict__ gate, const float* __restrict__ ca_sig,
    const float* __restrict__ mu_g, const float* __restrict__ isd_g,
    const float* __restrict__ gamma, const float* __restrict__ beta,
    float* __restrict__ out) {
    const int hw0 = blockIdx.x * 64, o0 = blockIdx.y * 128, n = blockIdx.z;
    f32x4 acc_a[2][4] = {};
    f32x4 acc_b[2][4] = {};
    mfma_core_pair(XUH, XUL, XDW, W4H, W4L, W3B, n, hw0, o0, acc_a, acc_b);
    const int lane = threadIdx.x & 63, wv = threadIdx.x >> 6;
    const int quad = lane >> 4, nlo = lane & 15;
    const float cgb0 = cgb[0];
#pragma unroll
    for (int f = 0; f < 2; ++f) {
        const int om = o0 + f * 64 + wv * 16 + quad * 4;
#pragma unroll
        for (int nt = 0; nt < 4; ++nt) {
            const int hw = hw0 + nt * 16 + nlo;
            const int pix = n * HW + hw;
            const float sp = sigmoidf_(s_pix[pix] + cgb0);
#pragma unroll
            for (int r = 0; r < 4; ++r) {
                const int o = om + r;
                const float g = gate[n * CC + o];
                const float cs = ca_sig[n * CC + o];
                const float mu = mu_g[n * 16 + (o >> 4)];
                const float isd = isd_g[n * 16 + (o >> 4)];
                const size_t rowi = ((size_t)(n * CC + o)) * HW + hw;
                const float xg = XG[rowi];
                const float gui = (sp * xg - mu) * isd * gamma[o] + beta[o];
                out[rowi] = (acc_b[f][nt][r] + b3[o]) * g + (acc_a[f][nt][r] + b4[o]) + gui + xg * cs;
            }
        }
    }
}

// grid N (16): rw=sigmoid(mean), ca conv1d(k=5,pad2)+sigmoid, group mu / 1/(sd+1e-10)
__global__ __launch_bounds__(256) void stats2_kernel(const float* __restrict__ sum_c,
                                                     const float* __restrict__ sq_c,
                                                     const float* __restrict__ caw,
                                                     float* __restrict__ rw,
                                                     float* __restrict__ ca_sig,
                                                     float* __restrict__ mu_g,
                                                     float* __restrict__ isd_g,
                                                     float* __restrict__ xlow_sum) {
    const int n = blockIdx.x, c = threadIdx.x;
    __shared__ float m[256];
    const float mean = sum_c[n * CC + c] * (1.f / (float)HW);
    m[c] = mean;
    rw[n * CC + c] = sigmoidf_(mean);
    xlow_sum[n * CC + c] = 0.f;
    __syncthreads();
    float y = 0.f;
#pragma unroll
    for (int k = 0; k < 5; ++k) {
        const int cc = c - 2 + k;
        if (cc >= 0 && cc < 256) y += m[cc] * caw[k];
    }
    ca_sig[n * CC + c] = sigmoidf_(y);
    if (c < 16) {
        float S = 0.f, Q = 0.f;
        for (int j = 0; j < 16; ++j) {
            S += sum_c[n * CC + c * 16 + j];
            Q += sq_c[n * CC + c * 16 + j];
        }
        const float cnt = 65536.f;
        const float mu = S / cnt;
        float var = (Q - S * S / cnt) * (1.f / (cnt - 1.f));
        var = fmaxf(var, 0.f);
        mu_g[n * 16 + c] = mu;
        isd_g[n * 16 + c] = 1.f / (sqrtf(var) + 1e-10f);
    }
}

// ---------------------------------------------------------------------------
// Fused masks + conv4-input transpose/split ([n][HW][C] layout).
// grid (HW/64, CC/64, N)
// ---------------------------------------------------------------------------
__global__ __launch_bounds__(256) void masks_split_kernel(
    float* g1_xlow,  // aliased in/out
    const float* __restrict__ XG,
    const float* __restrict__ rw,
    const float* __restrict__ bng, const float* __restrict__ bnb,
    const float* __restrict__ bnrm, const float* __restrict__ bnrv,
    unsigned short* __restrict__ O0, unsigned short* __restrict__ O1,
    float* __restrict__ xlow_sum) {
    const int hw0 = blockIdx.x * 64, c0 = blockIdx.y * 64, n = blockIdx.z;
    __shared__ float sT[64][65];
    const int tid = threadIdx.x;
    const int cl = tid >> 2;
    const int q = tid & 3;
    const int c = c0 + cl;
    const float inv = bng[c] / sqrtf(bnrv[c] + 1e-5f);
    const float off = bnb[c] - bnrm[c] * inv;
    const float rwv = rw[n * CC + c];
    const size_t rowb = ((size_t)(n * CC + c)) * HW + hw0;
    float lsum = 0.f;
#pragma unroll
    for (int j = 0; j < 4; ++j) {
        const int hwl = q * 4 + j * 16;
        const float4 a = *(const float4*)(g1_xlow + rowb + hwl);
        const float4 x = *(const float4*)(XG + rowb + hwl);
        const float* ap = &a.x; const float* xp = &x.x;
        float4 xlv;
        float* xlp = &xlv.x;
#pragma unroll
        for (int e = 0; e < 4; ++e) {
            const float g2e = xp[e] - ap[e];            // reconstruct g2
            const float w1 = sigmoidf_(inv * ap[e] + off);
            const float w2 = sigmoidf_(inv * g2e + off);
            const float cu = (rwv >= w1 ? 1.f : 0.f) + (rwv >= w2 ? 1.f : 0.f);
            const float xu = xp[e] * cu;
            const float xl = xp[e] * (2.f - cu);
            sT[cl][hwl + e] = xu;
            xlp[e] = xl;
            lsum += xl;
        }
        *(float4*)(g1_xlow + rowb + hwl) = xlv;
    }
    lsum += __shfl_xor(lsum, 1);
    lsum += __shfl_xor(lsum, 2);
    if (q == 0) atomicAdd(&xlow_sum[n * CC + c], lsum);
    __syncthreads();
    const int hwl2 = tid >> 2, cb = (tid & 3) << 4;
    unsigned short h[16], m[16];
#pragma unroll
    for (int j = 0; j < 16; ++j) {
        const float x = sT[cb + j][hwl2];
        const unsigned short hh = bf16_rne(x);
        h[j] = hh;
        m[j] = bf16_rne(x - bf16_tof(hh));
    }
    const size_t ob = ((size_t)(n * HW + hw0 + hwl2)) * 256 + c0 + cb;
    *(int4*)(O0 + ob) = *(int4*)&h[0]; *(int4*)(O0 + ob + 8) = *(int4*)&h[8];
    *(int4*)(O1 + ob) = *(int4*)&m[0]; *(int4*)(O1 + ob + 8) = *(int4*)&m[8];
}

// grid N: gate = softmax_c(relu(xlow_mean @ gate_w^T + gate_b))
__global__ __launch_bounds__(256) void gate_kernel(const float* __restrict__ xlow_sum,
                                                   const float* __restrict__ gatew,
                                                   const float* __restrict__ gateb,
                                                   float* __restrict__ gate) {
    const int n = blockIdx.x, c = threadIdx.x;
    __shared__ float xm[256];
    __shared__ float red[256];
    xm[c] = xlow_sum[n * CC + c] * (1.f / (float)HW);
    __syncthreads();
    float acc = gateb[c];
    const float* wr = gatew + (size_t)c * 256;
#pragma unroll 8
    for (int k = 0; k < 256; ++k) acc += xm[k] * wr[k];
    const float v = fmaxf(acc, 0.f);
    red[c] = v;
    __syncthreads();
    for (int s = 128; s > 0; s >>= 1) {
        if (c < s) red[c] = fmaxf(red[c], red[c + s]);
        __syncthreads();
    }
    const float mx = red[0];
    __syncthreads();
    const float e = expf(v - mx);
    red[c] = e;
    __syncthreads();
    for (int s = 128; s > 0; s >>= 1) {
        if (c < s) red[c] += red[c + s];
        __syncthreads();
    }
    gate[n * CC + c] = e / red[0];
}

// grid NC: depthwise 3x3 (pad 1) on x_low via LDS slab. Writes bf16 directly
// ([n][C][HW] ushort) — the conv3 GEMM consumes bf16 anyway, so this is the
// same single RNE rounding as the old fp32->tsplit<1> path, at half traffic.
__global__ __launch_bounds__(256) void dwconv_kernel(const float* __restrict__ xlow,
                                                     const float* __restrict__ dww,
                                                     const float* __restrict__ dwb,
                                                     unsigned short* __restrict__ out) {
    const int c = blockIdx.x & 255;
    __shared__ float sl[64][65];
    const size_t base = (size_t)blockIdx.x * HW;
    for (int r = 0; r < 16; ++r) {
        const int idx = threadIdx.x + r * 256;
        sl[idx >> 6][idx & 63] = xlow[base + idx];
    }
    float wk[9];
#pragma unroll
    for (int j = 0; j < 9; ++j) wk[j] = dww[c * 9 + j];
    const float bias = dwb[c];
    __syncthreads();
    for (int r = 0; r < 16; ++r) {
        const int idx = threadIdx.x + r * 256;
        const int h = idx >> 6, w = idx & 63;
        float acc = bias;
#pragma unroll
        for (int dh = 0; dh < 3; ++dh) {
            const int hh = h + dh - 1;
            if (hh < 0 || hh > 63) continue;
#pragma unroll
            for (int dw2 = 0; dw2 < 3; ++dw2) {
                const int ww2 = w + dw2 - 1;
                if (ww2 < 0 || ww2 > 63) continue;
                acc += sl[hh][ww2] * wk[dh * 3 + dw2];
            }
        }
        out[base + idx] = bf16_rne(acc);
    }
}

// grid NC: xh[n,c,h]=mean_w xL, xw[n,c,w]=mean_h xL
__global__ __launch_bounds__(256) void pool_kernel(const float* __restrict__ xL,
                                                   float* __restrict__ xh,
                                                   float* __restrict__ xw) {
    __shared__ float sl[64][65];
    const size_t base = (size_t)blockIdx.x * HW;
    for (int r = 0; r < 16; ++r) {
        const int idx = threadIdx.x + r * 256;
        sl[idx >> 6][idx & 63] = xL[base + idx];
    }
    __syncthreads();
    const int t = threadIdx.x;
    if (t < 64) {
        float s = 0.f;
        for (int w = 0; w < 64; ++w) s += sl[t][w];
        xh[(size_t)blockIdx.x * 64 + t] = s * (1.f / 64.f);
    } else if (t < 128) {
        const int w = t - 64;
        float s = 0.f;
        for (int h = 0; h < 64; ++h) s += sl[h][w];
        xw[(size_t)blockIdx.x * 64 + w] = s * (1.f / 64.f);
    }
}

// grid N: yc = relu(bn(la1 @ [xh;xw])); sh = sig(fh@yc_h), sw = sig(fw@yc_w)
__global__ __launch_bounds__(256) void local_att_kernel(const float* __restrict__ xh,
                                                        const float* __restrict__ xw,
                                                        const float* __restrict__ la1w,
                                                        const float* __restrict__ lag,
                                                        const float* __restrict__ lab,
                                                        const float* __restrict__ larm,
                                                        const float* __restrict__ larv,
                                                        const float* __restrict__ fhw,
                                                        const float* __restrict__ fww,
                                                        float* __restrict__ sh,
                                                        float* __restrict__ sw) {
    const int n = blockIdx.x;
    __shared__ float w1s[16 * 256];
    __shared__ float fhs[256 * 16];
    __shared__ float fws[256 * 16];
    __shared__ float ycs[16][128];
    for (int i = threadIdx.x; i < 4096; i += 256) {
        w1s[i] = la1w[i];
        fhs[i] = fhw[i];
        fws[i] = fww[i];
    }
    __syncthreads();
    for (int idx = threadIdx.x; idx < 2048; idx += 256) {
        const int m = idx >> 7, p = idx & 127;
        const float* vsrc = (p < 64) ? (xh + (size_t)n * CC * 64 + p)
                                     : (xw + (size_t)n * CC * 64 + (p - 64));
        float acc = 0.f;
#pragma unroll 8
        for (int c = 0; c < 256; ++c) acc += w1s[m * 256 + c] * vsrc[(size_t)c * 64];
        const float inv = lag[m] / sqrtf(larv[m] + 1e-5f);
        const float off = lab[m] - larm[m] * inv;
        ycs[m][p] = fmaxf(inv * acc + off, 0.f);
    }
    __syncthreads();
    for (int idx = threadIdx.x; idx < 16384; idx += 256) {
        const int c = idx >> 6, h = idx & 63;
        float a1 = 0.f, a2 = 0.f;
#pragma unroll
        for (int m = 0; m < 16; ++m) {
            a1 += fhs[c * 16 + m] * ycs[m][h];
            a2 += fws[c * 16 + m] * ycs[m][64 + h];
        }
        sh[(size_t)n * CC * 64 + idx] = sigmoidf_(a1);
        sw[(size_t)n * CC * 64 + idx] = sigmoidf_(a2);
    }
}

// grid NC: out = xL * sh[h]*sw[w]  (out-of-place: xL in workspace, out = d_out)
__global__ __launch_bounds__(256) void final_kernel(const float* __restrict__ xL,
                                                    const float* __restrict__ sh,
                                                    const float* __restrict__ sw,
                                                    float* __restrict__ out) {
    __shared__ float shs[64], sws[64];
    const int t = threadIdx.x;
    if (t < 64) shs[t] = sh[(size_t)blockIdx.x * 64 + t];
    else if (t < 128) sws[t - 64] = sw[(size_t)blockIdx.x * 64 + (t - 64)];
    __syncthreads();
    const size_t base = (size_t)blockIdx.x * HW;
#pragma unroll 4
    for (int r = 0; r < 16; ++r) {
        const int idx = t + r * 256;
        out[base + idx] = xL[base + idx] * shs[idx >> 6] * sws[idx & 63];
    }
}

extern "C" void kernel_launch(void* const* d_in, const int* in_sizes, int n_in,
                              void* d_out, int out_size, void* d_ws, size_t ws_size,
                              hipStream_t stream) {
    const float* x1 = (const float*)d_in[0];
    const float* x2 = (const float*)d_in[1];
    const float* c1w = (const float*)d_in[2];
    const float* c1b = (const float*)d_in[3];
    const float* c2w = (const float*)d_in[4];
    const float* c2b = (const float*)d_in[5];
    const float* c3w = (const float*)d_in[6];
    const float* c3b = (const float*)d_in[7];
    const float* c4w = (const float*)d_in[8];
    const float* c4b = (const float*)d_in[9];
    const float* cgw = (const float*)d_in[10];
    const float* cgb = (const float*)d_in[11];
    const float* bng = (const float*)d_in[12];
    const float* bnb = (const float*)d_in[13];
    const float* bnrm = (const float*)d_in[14];
    const float* bnrv = (const float*)d_in[15];
    const float* gamma = (const float*)d_in[16];
    const float* beta = (const float*)d_in[17];
    const float* gatew = (const float*)d_in[18];
    const float* gateb = (const float*)d_in[19];
    const float* dww = (const float*)d_in[20];
    const float* dwb = (const float*)d_in[21];
    // d_in[22], d_in[23]: interact_w/b — dead code (softmax over size-1 axis == 1)
    const float* caw = (const float*)d_in[24];
    const float* la1w = (const float*)d_in[25];
    const float* lag = (const float*)d_in[26];
    const float* lab = (const float*)d_in[27];
    const float* larm = (const float*)d_in[28];
    const float* larv = (const float*)d_in[29];
    const float* fhw = (const float*)d_in[30];
    const float* fww = (const float*)d_in[31];

    // ---- Workspace plan ----
    // buf0: g1 -> x_low (in place) -> dw split ushorts [n][HW][C]
    // buf1: [conv1 splits hi,mid] -> XG (alive through gemm_final)
    // buf2: [conv1/conv2 lo split] -> dw bf16 [n][C][HW] -> xL (gemm_final out)
    // d_out: [conv2 splits hi,mid] -> [x_up splits hi,lo] -> final out
    float* ws = (float*)d_ws;
    float* buf0 = ws;
    float* buf1 = ws + FSZ;
    float* buf2 = ws + 2 * FSZ;
    float* sp = ws + 3 * FSZ;
    float* sum_c = sp;    sp += 4096;   // later reused as gate
    float* sq_c = sp;     sp += 4096;   // contiguous with sum_c (zeroed together)
    float* rw = sp;       sp += 4096;
    float* ca_sig = sp;   sp += 4096;
    float* xlow_sum = sp; sp += 4096;
    float* mu_g = sp;     sp += 256;
    float* isd_g = sp;    sp += 256;
    float* s_pix = sp;    sp += (size_t)NN * HW;       // 65536, raw (pre-sigmoid)
    float* xh = sp;       sp += (size_t)NN * CC * 64;  // 262144
    float* xwb = sp;      sp += (size_t)NN * CC * 64;
    float* shb = sp;      sp += (size_t)NN * CC * 64;
    float* swb = sp;      sp += (size_t)NN * CC * 64;
    // weight splits overlap shb/swb (written only at step 10; weights dead by then)
    unsigned short* wsp = (unsigned short*)shb;
    unsigned short* w1h = wsp + 0 * 65536;
    unsigned short* w1m = wsp + 1 * 65536;
    unsigned short* w1l = wsp + 2 * 65536;
    unsigned short* w2h = wsp + 3 * 65536;
    unsigned short* w2m = wsp + 4 * 65536;
    unsigned short* w2l = wsp + 5 * 65536;
    unsigned short* w4h = wsp + 6 * 65536;
    unsigned short* w4l = wsp + 7 * 65536;
    unsigned short* w3b = wsp + 8 * 65536;

    float* out = (float*)d_out;

    const dim3 gt(HW / 64, CC / 64, NN);   // tsplit/masks grids (64, 4, 16)
    const dim3 gg(HW / 64, CC / 128, NN);  // gemm grids (64, 2, 16)

    // 0: weight splits (fragment order) + zero sum_c/sq_c and s_pix accumulators
    wsplit_kernel<<<256, 256, 0, stream>>>(c1w, c2w, c3w, c4w, w1h, w1m, w1l,
                                           w2h, w2m, w2l, w4h, w4l, w3b,
                                           sum_c, s_pix);
    // 1: g1 = conv1(x1)  (3-split ~fp32 MFMA). Splits: buf1 (hi,mid) + buf2 (lo).
    {
        unsigned short* sx0 = (unsigned short*)buf1;
        unsigned short* sx1 = (unsigned short*)buf1 + FSZ;
        unsigned short* sx2 = (unsigned short*)buf2;
        tsplit3_kernel<<<gt, 256, 0, stream>>>(x1, sx0, sx1, sx2);
        gemm_mfma_kernel<3><<<gg, 256, 0, stream>>>(sx0, sx1, sx2, w1h, w1m, w1l, c1b, buf0);
    }
    // 2: XG = conv2(x2) + g1 fused. Splits: d_out (hi,mid) + buf2 (lo).
    //    Epilogue also accumulates sum_c/sq_c (XG stats) and s_pix (conv4g dot).
    {
        unsigned short* sx0 = (unsigned short*)out;
        unsigned short* sx1 = (unsigned short*)out + FSZ;
        unsigned short* sx2 = (unsigned short*)buf2;
        tsplit3_kernel<<<gt, 256, 0, stream>>>(x2, sx0, sx1, sx2);
        gemm_xg_kernel<<<gg, 256, 0, stream>>>(sx0, sx1, sx2, w2h, w2m, w2l, c2b,
                                               buf0, cgw, buf1, sum_c, sq_c, s_pix);
    }
    // 3: rw, channel-att sigmoid, group mu/invsd (+ zero xlow_sum)
    stats2_kernel<<<NN, 256, 0, stream>>>(sum_c, sq_c, caw, rw, ca_sig, mu_g, isd_g, xlow_sum);
    // 4: fused masks + conv4-input split (g2 = XG - g1): x_low -> buf0 (in place),
    //    x_up splits -> d_out, xlow_sum via atomics (zeroed in step 3)
    {
        unsigned short* ux0 = (unsigned short*)out;
        unsigned short* ux1 = (unsigned short*)out + FSZ;
        masks_split_kernel<<<gt, 256, 0, stream>>>(buf0, buf1, rw, bng, bnb, bnrm, bnrv,
                                                   ux0, ux1, xlow_sum);
    }
    // 5: gate softmax (output reuses sum_c)
    float* gate = sum_c;
    gate_kernel<<<NN, 256, 0, stream>>>(xlow_sum, gatew, gateb, gate);
    // 6: dwconv on x_low (buf0) -> bf16 [n][C][HW] in buf2 (lo splits dead)
    dwconv_kernel<<<NN * CC, 256, 0, stream>>>(buf0, dww, dwb, (unsigned short*)buf2);
    // 7: transpose dw bf16 -> [n][HW][C] split in buf0 (x_low dead)
    tsplit_bf16_kernel<<<gt, 256, 0, stream>>>((const unsigned short*)buf2,
                                               (unsigned short*)buf0);
    // 8: merged conv4+conv3 GEMM + final combine -> xL in buf2 (dw bf16 dead).
    //    Reads x_up splits (d_out), dw split (buf0), XG (buf1).
    {
        unsigned short* ux0 = (unsigned short*)out;
        unsigned short* ux1 = (unsigned short*)out + FSZ;
        unsigned short* sx0 = (unsigned short*)buf0;
        gemm_final_kernel<<<gg, 256, 0, stream>>>(ux0, ux1, sx0, w4h, w4l, w3b,
                                                  c3b, c4b, buf1, s_pix, cgb,
                                                  gate, ca_sig, mu_g, isd_g, gamma, beta,
                                                  buf2);
    }
    // 9: pools (read xL from buf2)
    pool_kernel<<<NN * CC, 256, 0, stream>>>(buf2, xh, xwb);
    // 10: coordinate attention -> sh, sw (overwrites weight-split region — weights dead)
    local_att_kernel<<<NN, 256, 0, stream>>>(xh, xwb, la1w, lag, lab, larm, larv,
                                             fhw, fww, shb, swb);
    // 11: out = xL * sh*sw  (buf2 -> d_out; x_up splits in d_out are dead)
    final_kernel<<<NN * CC, 256, 0, stream>>>(buf2, shb, swb, out);
}

// Round 9
// 634.157 us; speedup vs baseline: 1.0840x; 1.0054x over previous
//
#include <hip/hip_runtime.h>
#include <cstddef>
#include <cstdint>

// Problem constants (fixed by reference setup_inputs)
constexpr int NN = 16, CC = 256, HH = 64, WW = 64, HW = 64 * 64; // 4096
constexpr size_t FSZ = (size_t)NN * CC * HW;                      // 16,777,216

typedef short bf16x8 __attribute__((ext_vector_type(8)));
typedef float f32x4 __attribute__((ext_vector_type(4)));

__device__ __forceinline__ float sigmoidf_(float x) { return 1.f / (1.f + expf(-x)); }

__device__ __forceinline__ unsigned short bf16_rne(float f) {
    uint32_t u = __builtin_bit_cast(uint32_t, f);
    u += 0x7FFFu + ((u >> 16) & 1u);
    return (unsigned short)(u >> 16);
}
__device__ __forceinline__ float bf16_tof(unsigned short h) {
    uint32_t u = ((uint32_t)h) << 16;
    return __builtin_bit_cast(float, u);
}

// Direct global->LDS DMA, 16B per lane. LDS dest = wave-uniform base + lane*16.
__device__ __forceinline__ void gload16(const void* g, void* l) {
    __builtin_amdgcn_global_load_lds((const __attribute__((address_space(1))) void*)g,
                                     (__attribute__((address_space(3))) void*)l, 16, 0, 0);
}

// ---------------------------------------------------------------------------
// W fragment-order layout (A-operand), logical (o, k) of a 256x256 matrix:
//   elem = ((o>>4)*8 + (k>>5))*512 + ((k&31)>>3)*128 + (o&15)*8 + (k&7)
//
// R9: counted-vmcnt pipeline (T4). X tiles TRIPLE-buffered in linear LDS
// [64][32]us with the R6-verified XOR chunk swizzle (pre-swizzled global src,
// linear DMA dest, swizzled ds_read). Per k-step: issue W prefetch (6 loads),
// issue X DMA for tile ks+2 (3 loads), MFMA, then
//   s_waitcnt vmcnt(3)   <- newest 3 (tile ks+2) may stay in flight;
//                           own tile ks+1 + W loads proven complete
//   s_barrier (raw)      <- all waves' DMAs for tile ks+1 landed
//   sched_barrier(0)     <- fence: no ds_read hoists above the barrier
// Never drains vmcnt to 0 in the loop (the structural ~20% stall of
// __syncthreads). Numerics identical to R8 (same MFMA order/operands);
// absmax is the race canary.
// ---------------------------------------------------------------------------

// ---------------------------------------------------------------------------
// Weight split -> fragment order. Also zeroes sum_c/sq_c and s_pix.
// ---------------------------------------------------------------------------
__global__ __launch_bounds__(256) void wsplit_kernel(
    const float* __restrict__ w1, const float* __restrict__ w2,
    const float* __restrict__ w3, const float* __restrict__ w4,
    unsigned short* __restrict__ w1h, unsigned short* __restrict__ w1m, unsigned short* __restrict__ w1l,
    unsigned short* __restrict__ w2h, unsigned short* __restrict__ w2m, unsigned short* __restrict__ w2l,
    unsigned short* __restrict__ w4h, unsigned short* __restrict__ w4l,
    unsigned short* __restrict__ w3b,
    float* __restrict__ zstat, float* __restrict__ zspix) {
    const int i = blockIdx.x * 256 + threadIdx.x;  // 65536 weights each
    const int o = i >> 8, c = i & 255;
    const size_t fo = ((size_t)((o >> 4) * 8 + (c >> 5))) * 512 +
                      (size_t)(((c & 31) >> 3) * 128 + (o & 15) * 8 + (c & 7));
    {
        float x = w1[i];
        unsigned short h = bf16_rne(x); float r = x - bf16_tof(h);
        unsigned short m = bf16_rne(r); float r2 = r - bf16_tof(m);
        w1h[fo] = h; w1m[fo] = m; w1l[fo] = bf16_rne(r2);
    }
    {
        float x = w2[i];
        unsigned short h = bf16_rne(x); float r = x - bf16_tof(h);
        unsigned short m = bf16_rne(r); float r2 = r - bf16_tof(m);
        w2h[fo] = h; w2m[fo] = m; w2l[fo] = bf16_rne(r2);
    }
    {
        float x = w4[i];
        unsigned short h = bf16_rne(x); float r = x - bf16_tof(h);
        w4h[fo] = h; w4l[fo] = bf16_rne(r);
    }
    w3b[fo] = bf16_rne(w3[i]);
    if (i < 8192) zstat[i] = 0.f;   // sum_c (4096) + sq_c (4096), contiguous
    zspix[i] = 0.f;                 // s_pix raw accumulator (NN*HW = 65536)
}

// ---------------------------------------------------------------------------
// Transpose + split: X fp32 [n][C][HW] -> 3 bf16 arrays [n][HW][C]
// grid (HW/64, C/64, N), 256 threads
// ---------------------------------------------------------------------------
__global__ __launch_bounds__(256) void tsplit3_kernel(const float* __restrict__ X,
                                                      unsigned short* __restrict__ O0,
                                                      unsigned short* __restrict__ O1,
                                                      unsigned short* __restrict__ O2) {
    const int hw0 = blockIdx.x * 64, c0 = blockIdx.y * 64, n = blockIdx.z;
    __shared__ float sT[64][65];
    const int tid = threadIdx.x;
    {
        const int hwl = (tid & 15) << 2;
        const int cl = tid >> 4;  // 0..15
#pragma unroll
        for (int p = 0; p < 4; ++p) {
            const int c = cl + p * 16;
            const float4 v = *(const float4*)(X + ((size_t)(n * CC + c0 + c)) * HW + hw0 + hwl);
            sT[c][hwl] = v.x; sT[c][hwl + 1] = v.y; sT[c][hwl + 2] = v.z; sT[c][hwl + 3] = v.w;
        }
    }
    __syncthreads();
    const int hwl = tid >> 2, cb = (tid & 3) << 4;
    unsigned short h[16], m[16], l[16];
#pragma unroll
    for (int j = 0; j < 16; ++j) {
        const float x = sT[cb + j][hwl];
        const unsigned short hh = bf16_rne(x);
        h[j] = hh;
        const float r = x - bf16_tof(hh);
        const unsigned short mm = bf16_rne(r);
        m[j] = mm;
        l[j] = bf16_rne(r - bf16_tof(mm));
    }
    const size_t ob = ((size_t)(n * HW + hw0 + hwl)) * 256 + c0 + cb;
    *(int4*)(O0 + ob) = *(int4*)&h[0]; *(int4*)(O0 + ob + 8) = *(int4*)&h[8];
    *(int4*)(O1 + ob) = *(int4*)&m[0]; *(int4*)(O1 + ob + 8) = *(int4*)&m[8];
    *(int4*)(O2 + ob) = *(int4*)&l[0]; *(int4*)(O2 + ob + 8) = *(int4*)&l[8];
}

// ---------------------------------------------------------------------------
// Transpose (bf16 in, bf16 out): X ushort [n][C][HW] -> [n][HW][C]
// grid (HW/64, C/64, N). Used for the dw -> conv3 input path.
// ---------------------------------------------------------------------------
__global__ __launch_bounds__(256) void tsplit_bf16_kernel(const unsigned short* __restrict__ X,
                                                          unsigned short* __restrict__ O0) {
    const int hw0 = blockIdx.x * 64, c0 = blockIdx.y * 64, n = blockIdx.z;
    __shared__ unsigned short sT[64][72];   // pad 72 us (144B rows)
    const int tid = threadIdx.x;
    {
        const int cl = tid >> 3;            // 0..31
        const int ch = (tid & 7) * 8;       // 8-us chunk
#pragma unroll
        for (int p = 0; p < 2; ++p) {
            const int c = cl + p * 32;
            const int4 v = *(const int4*)(X + ((size_t)(n * CC + c0 + c)) * HW + hw0 + ch);
            *(int4*)&sT[c][ch] = v;
        }
    }
    __syncthreads();
    const int hwl = tid >> 2, cb = (tid & 3) << 4;
    unsigned short h[16];
#pragma unroll
    for (int j = 0; j < 16; ++j) h[j] = sT[cb + j][hwl];
    const size_t ob = ((size_t)(n * HW + hw0 + hwl)) * 256 + c0 + cb;
    *(int4*)(O0 + ob) = *(int4*)&h[0]; *(int4*)(O0 + ob + 8) = *(int4*)&h[8];
}

// ---------------------------------------------------------------------------
// MFMA GEMM core v8 (counted vmcnt, triple-buffered X): 3 split arrays,
// tile 128(o) x 64(hw), K=256 in steps of 32, 4 waves.
// acc[f][nt]: o = o0 + f*64 + wv*16 + quad*4 + reg, hw = hw0 + nt*16 + (lane&15)
// ---------------------------------------------------------------------------
__device__ __forceinline__ void mfma_core8(const unsigned short* __restrict__ X0,
                                           const unsigned short* __restrict__ X1,
                                           const unsigned short* __restrict__ X2,
                                           const unsigned short* __restrict__ W0,
                                           const unsigned short* __restrict__ W1,
                                           const unsigned short* __restrict__ W2,
                                           int n, int hw0, int o0, f32x4 (&acc)[2][4]) {
    __shared__ unsigned short sX[3][3][64][32];   // triple buffer, linear
    const int tid = threadIdx.x;
    const int lane = tid & 63, wv = tid >> 6, quad = lane >> 4, nlo = lane & 15;
    const int srow = tid >> 2;                          // staging row 0..63
    const int schunk = (tid & 3) ^ ((srow >> 1) & 3);   // pre-swizzled source chunk
    const unsigned short* Xs[3] = {X0, X1, X2};
    const unsigned short* Ws[3] = {W0, W1, W2};
    const size_t xg = ((size_t)(n * HW + hw0 + srow)) * 256 + schunk * 8;
    const unsigned short* wp[3];
#pragma unroll
    for (int s = 0; s < 3; ++s)
        wp[s] = Ws[s] + ((size_t)((o0 >> 4) + wv) * 8) * 512 + (size_t)lane * 8;

    // swizzled LDS read offsets (ushort index within one [64][32] tile)
    int roff[4];
#pragma unroll
    for (int nt = 0; nt < 4; ++nt) {
        const int rrow = nt * 16 + nlo;
        roff[nt] = rrow * 32 + (quad ^ ((rrow >> 1) & 3)) * 8;
    }

    bf16x8 af[2][3][2];
    // prologue: [tile0 DMA (3)] [W k0 (6)] [tile1 DMA (3)]
#pragma unroll
    for (int s = 0; s < 3; ++s)
        gload16(Xs[s] + xg, &sX[0][s][wv * 16][0]);
#pragma unroll
    for (int s = 0; s < 3; ++s)
#pragma unroll
        for (int f = 0; f < 2; ++f)
            af[0][s][f] = *(const bf16x8*)(wp[s] + ((size_t)(f * 32)) * 512);
#pragma unroll
    for (int s = 0; s < 3; ++s)
        gload16(Xs[s] + xg + 32, &sX[1][s][wv * 16][0]);
    // allow newest 9 (af0 6 + tile1 3) in flight; own tile0 proven complete
    asm volatile("s_waitcnt vmcnt(9)" ::: "memory");
    __builtin_amdgcn_s_barrier();
    __builtin_amdgcn_sched_barrier(0);

#pragma unroll
    for (int ks = 0; ks < 8; ++ks) {
        const int cur = ks % 3;
        const int c2 = ks & 1;
        // issue W prefetch for ks+1 (6 loads)
        if (ks < 7) {
#pragma unroll
            for (int s = 0; s < 3; ++s)
#pragma unroll
                for (int f = 0; f < 2; ++f)
                    af[c2 ^ 1][s][f] = *(const bf16x8*)(wp[s] + ((size_t)(f * 32 + ks + 1)) * 512);
        }
        // issue X DMA for tile ks+2 (3 loads) — 2 k-steps of cover
        if (ks < 6) {
#pragma unroll
            for (int s = 0; s < 3; ++s)
                gload16(Xs[s] + xg + (ks + 2) * 32, &sX[(ks + 2) % 3][s][wv * 16][0]);
        }
#pragma unroll
        for (int nt = 0; nt < 4; ++nt) {
            bf16x8 bfr[3];
#pragma unroll
            for (int s = 0; s < 3; ++s)
                bfr[s] = *(const bf16x8*)&sX[cur][s][0][roff[nt]];
#pragma unroll
            for (int f = 0; f < 2; ++f) {
                // smallest-magnitude-first order (identical to R8)
                acc[f][nt] = __builtin_amdgcn_mfma_f32_16x16x32_bf16(af[c2][1][f], bfr[1], acc[f][nt], 0, 0, 0);
                acc[f][nt] = __builtin_amdgcn_mfma_f32_16x16x32_bf16(af[c2][0][f], bfr[2], acc[f][nt], 0, 0, 0);
                acc[f][nt] = __builtin_amdgcn_mfma_f32_16x16x32_bf16(af[c2][2][f], bfr[0], acc[f][nt], 0, 0, 0);
                acc[f][nt] = __builtin_amdgcn_mfma_f32_16x16x32_bf16(af[c2][0][f], bfr[1], acc[f][nt], 0, 0, 0);
                acc[f][nt] = __builtin_amdgcn_mfma_f32_16x16x32_bf16(af[c2][1][f], bfr[0], acc[f][nt], 0, 0, 0);
                acc[f][nt] = __builtin_amdgcn_mfma_f32_16x16x32_bf16(af[c2][0][f], bfr[0], acc[f][nt], 0, 0, 0);
            }
        }
        // counted drain: own tile ks+1 (+W) complete; tile ks+2 stays in flight
        if (ks < 6) {
            asm volatile("s_waitcnt vmcnt(3)" ::: "memory");
            __builtin_amdgcn_s_barrier();
            __builtin_amdgcn_sched_barrier(0);
        } else if (ks == 6) {
            asm volatile("s_waitcnt vmcnt(6)" ::: "memory");  // af7 (6) may fly
            __builtin_amdgcn_s_barrier();
            __builtin_amdgcn_sched_barrier(0);
        }
    }
}

// ---------------------------------------------------------------------------
// Paired-product core v8 (merged conv4+conv3), same counted-vmcnt staging.
// acc_a gets conv4's 3 split-products, acc_b conv3's single product.
// ---------------------------------------------------------------------------
__device__ __forceinline__ void mfma_core_pair8(const unsigned short* __restrict__ XUH,
                                                const unsigned short* __restrict__ XUL,
                                                const unsigned short* __restrict__ XDW,
                                                const unsigned short* __restrict__ W4H,
                                                const unsigned short* __restrict__ W4L,
                                                const unsigned short* __restrict__ W3B,
                                                int n, int hw0, int o0,
                                                f32x4 (&acc_a)[2][4], f32x4 (&acc_b)[2][4]) {
    __shared__ unsigned short sX[3][3][64][32];
    const int tid = threadIdx.x;
    const int lane = tid & 63, wv = tid >> 6, quad = lane >> 4, nlo = lane & 15;
    const int srow = tid >> 2;
    const int schunk = (tid & 3) ^ ((srow >> 1) & 3);
    const unsigned short* Xs[3] = {XUH, XUL, XDW};
    const unsigned short* Ws[3] = {W4H, W4L, W3B};
    const size_t xg = ((size_t)(n * HW + hw0 + srow)) * 256 + schunk * 8;
    const unsigned short* wp[3];
#pragma unroll
    for (int s = 0; s < 3; ++s)
        wp[s] = Ws[s] + ((size_t)((o0 >> 4) + wv) * 8) * 512 + (size_t)lane * 8;

    int roff[4];
#pragma unroll
    for (int nt = 0; nt < 4; ++nt) {
        const int rrow = nt * 16 + nlo;
        roff[nt] = rrow * 32 + (quad ^ ((rrow >> 1) & 3)) * 8;
    }

    bf16x8 af[2][3][2];
#pragma unroll
    for (int s = 0; s < 3; ++s)
        gload16(Xs[s] + xg, &sX[0][s][wv * 16][0]);
#pragma unroll
    for (int s = 0; s < 3; ++s)
#pragma unroll
        for (int f = 0; f < 2; ++f)
            af[0][s][f] = *(const bf16x8*)(wp[s] + ((size_t)(f * 32)) * 512);
#pragma unroll
    for (int s = 0; s < 3; ++s)
        gload16(Xs[s] + xg + 32, &sX[1][s][wv * 16][0]);
    asm volatile("s_waitcnt vmcnt(9)" ::: "memory");
    __builtin_amdgcn_s_barrier();
    __builtin_amdgcn_sched_barrier(0);

#pragma unroll
    for (int ks = 0; ks < 8; ++ks) {
        const int cur = ks % 3;
        const int c2 = ks & 1;
        if (ks < 7) {
#pragma unroll
            for (int s = 0; s < 3; ++s)
#pragma unroll
                for (int f = 0; f < 2; ++f)
                    af[c2 ^ 1][s][f] = *(const bf16x8*)(wp[s] + ((size_t)(f * 32 + ks + 1)) * 512);
        }
        if (ks < 6) {
#pragma unroll
            for (int s = 0; s < 3; ++s)
                gload16(Xs[s] + xg + (ks + 2) * 32, &sX[(ks + 2) % 3][s][wv * 16][0]);
        }
#pragma unroll
        for (int nt = 0; nt < 4; ++nt) {
            bf16x8 bfr[3];
#pragma unroll
            for (int s = 0; s < 3; ++s)
                bfr[s] = *(const bf16x8*)&sX[cur][s][0][roff[nt]];
#pragma unroll
            for (int f = 0; f < 2; ++f) {
                // conv4 (2-split cross, same order as R8)
                acc_a[f][nt] = __builtin_amdgcn_mfma_f32_16x16x32_bf16(af[c2][0][f], bfr[1], acc_a[f][nt], 0, 0, 0);
                acc_a[f][nt] = __builtin_amdgcn_mfma_f32_16x16x32_bf16(af[c2][1][f], bfr[0], acc_a[f][nt], 0, 0, 0);
                acc_a[f][nt] = __builtin_amdgcn_mfma_f32_16x16x32_bf16(af[c2][0][f], bfr[0], acc_a[f][nt], 0, 0, 0);
                // conv3 (plain bf16)
                acc_b[f][nt] = __builtin_amdgcn_mfma_f32_16x16x32_bf16(af[c2][2][f], bfr[2], acc_b[f][nt], 0, 0, 0);
            }
        }
        if (ks < 6) {
            asm volatile("s_waitcnt vmcnt(3)" ::: "memory");
            __builtin_amdgcn_s_barrier();
            __builtin_amdgcn_sched_barrier(0);
        } else if (ks == 6) {
            asm volatile("s_waitcnt vmcnt(6)" ::: "memory");
            __builtin_amdgcn_s_barrier();
            __builtin_amdgcn_sched_barrier(0);
        }
    }
}

// grid (HW/64, CC/128, N) — plain GEMM + bias (conv1 g1)
__global__ __launch_bounds__(256, 3) void gemm_mfma_kernel(
    const unsigned short* __restrict__ X0, const unsigned short* __restrict__ X1,
    const unsigned short* __restrict__ X2, const unsigned short* __restrict__ W0,
    const unsigned short* __restrict__ W1, const unsigned short* __restrict__ W2,
    const float* __restrict__ bias, float* __restrict__ Y) {
    const int hw0 = blockIdx.x * 64, o0 = blockIdx.y * 128, n = blockIdx.z;
    f32x4 acc[2][4] = {};
    mfma_core8(X0, X1, X2, W0, W1, W2, n, hw0, o0, acc);
    const int lane = threadIdx.x & 63, wv = threadIdx.x >> 6;
    const int quad = lane >> 4, nlo = lane & 15;
#pragma unroll
    for (int f = 0; f < 2; ++f) {
        const int om = o0 + f * 64 + wv * 16 + quad * 4;
#pragma unroll
        for (int nt = 0; nt < 4; ++nt) {
            const int hw = hw0 + nt * 16 + nlo;
#pragma unroll
            for (int r = 0; r < 4; ++r) {
                const int o = om + r;
                Y[((size_t)(n * CC + o)) * HW + hw] = acc[f][nt][r] + bias[o];
            }
        }
    }
}

// conv2 GEMM with fused XG formation + stats + conv4g partial dot.
__global__ __launch_bounds__(256, 3) void gemm_xg_kernel(
    const unsigned short* __restrict__ X0, const unsigned short* __restrict__ X1,
    const unsigned short* __restrict__ X2, const unsigned short* __restrict__ W0,
    const unsigned short* __restrict__ W1, const unsigned short* __restrict__ W2,
    const float* __restrict__ bias, const float* __restrict__ g1,
    const float* __restrict__ cgw,
    float* __restrict__ XG, float* __restrict__ sum_c, float* __restrict__ sq_c,
    float* __restrict__ s_pix) {
    const int hw0 = blockIdx.x * 64, o0 = blockIdx.y * 128, n = blockIdx.z;
    f32x4 acc[2][4] = {};
    mfma_core8(X0, X1, X2, W0, W1, W2, n, hw0, o0, acc);
    __shared__ float sRed[4][64];
    const int lane = threadIdx.x & 63, wv = threadIdx.x >> 6;
    const int quad = lane >> 4, nlo = lane & 15;
    float pnt[4] = {0.f, 0.f, 0.f, 0.f};
#pragma unroll
    for (int f = 0; f < 2; ++f) {
        const int om = o0 + f * 64 + wv * 16 + quad * 4;
#pragma unroll
        for (int r = 0; r < 4; ++r) {
            const int o = om + r;
            const float b = bias[o];
            const float wg = cgw[o];
            float s = 0.f, q = 0.f;
#pragma unroll
            for (int nt = 0; nt < 4; ++nt) {
                const int hw = hw0 + nt * 16 + nlo;
                const size_t rowi = ((size_t)(n * CC + o)) * HW + hw;
                const float xgv = acc[f][nt][r] + b + g1[rowi];
                XG[rowi] = xgv;
                s += xgv; q += xgv * xgv;
                pnt[nt] += wg * xgv;
            }
#pragma unroll
            for (int off = 1; off < 16; off <<= 1) { s += __shfl_xor(s, off); q += __shfl_xor(q, off); }
            if (nlo == 0) { atomicAdd(&sum_c[n * CC + o], s); atomicAdd(&sq_c[n * CC + o], q); }
        }
    }
#pragma unroll
    for (int nt = 0; nt < 4; ++nt) {
        float p = pnt[nt];
        p += __shfl_xor(p, 16); p += __shfl_xor(p, 32);
        if (quad == 0) sRed[wv][nt * 16 + nlo] = p;
    }
    __syncthreads();
    if (threadIdx.x < 64) {
        const float s2 = sRed[0][threadIdx.x] + sRed[1][threadIdx.x] +
                         sRed[2][threadIdx.x] + sRed[3][threadIdx.x];
        atomicAdd(&s_pix[n * HW + hw0 + threadIdx.x], s2);
    }
}

// Merged conv4+conv3 GEMM with fused final-combine epilogue:
// xL = (conv3(dw)+b3)*gate + (conv4(x_up)+b4) + gui + XG*ca_sig  -> xL buffer
__global__ __launch_bounds__(256, 3) void gemm_final_kernel(
    const unsigned short* __restrict__ XUH, const unsigned short* __restrict__ XUL,
    const unsigned short* __restrict__ XDW,
    const unsigned short* __restrict__ W4H, const unsigned short* __restrict__ W4L,
    const unsigned short* __restrict__ W3B,
    const float* __restrict__ b3, const float* __restrict__ b4,
    const float* __restrict__ XG, const float* __restrict__ s_pix,
    const float* __restrict__ cgb,
    const float* __restrict__ gate, const float* __restrict__ ca_sig,
    const float* __restrict__ mu_g, const float* __restrict__ isd_g,
    const float* __restrict__ gamma, const float* __restrict__ beta,
    float* __restrict__ out) {
    const int hw0 = blockIdx.x * 64, o0 = blockIdx.y * 128, n = blockIdx.z;
    f32x4 acc_a[2][4] = {};
    f32x4 acc_b[2][4] = {};
    mfma_core_pair8(XUH, XUL, XDW, W4H, W4L, W3B, n, hw0, o0, acc_a, acc_b);
    const int lane = threadIdx.x & 63, wv = threadIdx.x >> 6;
    const int quad = lane >> 4, nlo = lane & 15;
    const float cgb0 = cgb[0];
#pragma unroll
    for (int f = 0; f < 2; ++f) {
        const int om = o0 + f * 64 + wv * 16 + quad * 4;
#pragma unroll
        for (int nt = 0; nt < 4; ++nt) {
            const int hw = hw0 + nt * 16 + nlo;
            const int pix = n * HW + hw;
            const float sp = sigmoidf_(s_pix[pix] + cgb0);
#pragma unroll
            for (int r = 0; r < 4; ++r) {
                const int o = om + r;
                const float g = gate[n * CC + o];
                const float cs = ca_sig[n * CC + o];
                const float mu = mu_g[n * 16 + (o >> 4)];
                const float isd = isd_g[n * 16 + (o >> 4)];
                const size_t rowi = ((size_t)(n * CC + o)) * HW + hw;
                const float xg = XG[rowi];
                const float gui = (sp * xg - mu) * isd * gamma[o] + beta[o];
                out[rowi] = (acc_b[f][nt][r] + b3[o]) * g + (acc_a[f][nt][r] + b4[o]) + gui + xg * cs;
            }
        }
    }
}

// grid N (16): rw=sigmoid(mean), ca conv1d(k=5,pad2)+sigmoid, group mu / 1/(sd+1e-10)
__global__ __launch_bounds__(256) void stats2_kernel(const float* __restrict__ sum_c,
                                                     const float* __restrict__ sq_c,
                                                     const float* __restrict__ caw,
                                                     float* __restrict__ rw,
                                                     float* __restrict__ ca_sig,
                                                     float* __restrict__ mu_g,
                                                     float* __restrict__ isd_g,
                                                     float* __restrict__ xlow_sum) {
    const int n = blockIdx.x, c = threadIdx.x;
    __shared__ float m[256];
    const float mean = sum_c[n * CC + c] * (1.f / (float)HW);
    m[c] = mean;
    rw[n * CC + c] = sigmoidf_(mean);
    xlow_sum[n * CC + c] = 0.f;
    __syncthreads();
    float y = 0.f;
#pragma unroll
    for (int k = 0; k < 5; ++k) {
        const int cc = c - 2 + k;
        if (cc >= 0 && cc < 256) y += m[cc] * caw[k];
    }
    ca_sig[n * CC + c] = sigmoidf_(y);
    if (c < 16) {
        float S = 0.f, Q = 0.f;
        for (int j = 0; j < 16; ++j) {
            S += sum_c[n * CC + c * 16 + j];
            Q += sq_c[n * CC + c * 16 + j];
        }
        const float cnt = 65536.f;
        const float mu = S / cnt;
        float var = (Q - S * S / cnt) * (1.f / (cnt - 1.f));
        var = fmaxf(var, 0.f);
        mu_g[n * 16 + c] = mu;
        isd_g[n * 16 + c] = 1.f / (sqrtf(var) + 1e-10f);
    }
}

// ---------------------------------------------------------------------------
// Fused masks + conv4-input transpose/split ([n][HW][C] layout).
// grid (HW/64, CC/64, N)
// ---------------------------------------------------------------------------
__global__ __launch_bounds__(256) void masks_split_kernel(
    float* g1_xlow,  // aliased in/out
    const float* __restrict__ XG,
    const float* __restrict__ rw,
    const float* __restrict__ bng, const float* __restrict__ bnb,
    const float* __restrict__ bnrm, const float* __restrict__ bnrv,
    unsigned short* __restrict__ O0, unsigned short* __restrict__ O1,
    float* __restrict__ xlow_sum) {
    const int hw0 = blockIdx.x * 64, c0 = blockIdx.y * 64, n = blockIdx.z;
    __shared__ float sT[64][65];
    const int tid = threadIdx.x;
    const int cl = tid >> 2;
    const int q = tid & 3;
    const int c = c0 + cl;
    const float inv = bng[c] / sqrtf(bnrv[c] + 1e-5f);
    const float off = bnb[c] - bnrm[c] * inv;
    const float rwv = rw[n * CC + c];
    const size_t rowb = ((size_t)(n * CC + c)) * HW + hw0;
    float lsum = 0.f;
#pragma unroll
    for (int j = 0; j < 4; ++j) {
        const int hwl = q * 4 + j * 16;
        const float4 a = *(const float4*)(g1_xlow + rowb + hwl);
        const float4 x = *(const float4*)(XG + rowb + hwl);
        const float* ap = &a.x; const float* xp = &x.x;
        float4 xlv;
        float* xlp = &xlv.x;
#pragma unroll
        for (int e = 0; e < 4; ++e) {
            const float g2e = xp[e] - ap[e];            // reconstruct g2
            const float w1 = sigmoidf_(inv * ap[e] + off);
            const float w2 = sigmoidf_(inv * g2e + off);
            const float cu = (rwv >= w1 ? 1.f : 0.f) + (rwv >= w2 ? 1.f : 0.f);
            const float xu = xp[e] * cu;
            const float xl = xp[e] * (2.f - cu);
            sT[cl][hwl + e] = xu;
            xlp[e] = xl;
            lsum += xl;
        }
        *(float4*)(g1_xlow + rowb + hwl) = xlv;
    }
    lsum += __shfl_xor(lsum, 1);
    lsum += __shfl_xor(lsum, 2);
    if (q == 0) atomicAdd(&xlow_sum[n * CC + c], lsum);
    __syncthreads();
    const int hwl2 = tid >> 2, cb = (tid & 3) << 4;
    unsigned short h[16], m[16];
#pragma unroll
    for (int j = 0; j < 16; ++j) {
        const float x = sT[cb + j][hwl2];
        const unsigned short hh = bf16_rne(x);
        h[j] = hh;
        m[j] = bf16_rne(x - bf16_tof(hh));
    }
    const size_t ob = ((size_t)(n * HW + hw0 + hwl2)) * 256 + c0 + cb;
    *(int4*)(O0 + ob) = *(int4*)&h[0]; *(int4*)(O0 + ob + 8) = *(int4*)&h[8];
    *(int4*)(O1 + ob) = *(int4*)&m[0]; *(int4*)(O1 + ob + 8) = *(int4*)&m[8];
}

// grid N: gate = softmax_c(relu(xlow_mean @ gate_w^T + gate_b))
__global__ __launch_bounds__(256) void gate_kernel(const float* __restrict__ xlow_sum,
                                                   const float* __restrict__ gatew,
                                                   const float* __restrict__ gateb,
                                                   float* __restrict__ gate) {
    const int n = blockIdx.x, c = threadIdx.x;
    __shared__ float xm[256];
    __shared__ float red[256];
    xm[c] = xlow_sum[n * CC + c] * (1.f / (float)HW);
    __syncthreads();
    float acc = gateb[c];
    const float* wr = gatew + (size_t)c * 256;
#pragma unroll 8
    for (int k = 0; k < 256; ++k) acc += xm[k] * wr[k];
    const float v = fmaxf(acc, 0.f);
    red[c] = v;
    __syncthreads();
    for (int s = 128; s > 0; s >>= 1) {
        if (c < s) red[c] = fmaxf(red[c], red[c + s]);
        __syncthreads();
    }
    const float mx = red[0];
    __syncthreads();
    const float e = expf(v - mx);
    red[c] = e;
    __syncthreads();
    for (int s = 128; s > 0; s >>= 1) {
        if (c < s) red[c] += red[c + s];
        __syncthreads();
    }
    gate[n * CC + c] = e / red[0];
}

// grid NC: depthwise 3x3 (pad 1) on x_low via LDS slab. Writes bf16 directly
// ([n][C][HW] ushort) — same single RNE rounding as the old fp32 path.
__global__ __launch_bounds__(256) void dwconv_kernel(const float* __restrict__ xlow,
                                                     const float* __restrict__ dww,
                                                     const float* __restrict__ dwb,
                                                     unsigned short* __restrict__ out) {
    const int c = blockIdx.x & 255;
    __shared__ float sl[64][65];
    const size_t base = (size_t)blockIdx.x * HW;
    for (int r = 0; r < 16; ++r) {
        const int idx = threadIdx.x + r * 256;
        sl[idx >> 6][idx & 63] = xlow[base + idx];
    }
    float wk[9];
#pragma unroll
    for (int j = 0; j < 9; ++j) wk[j] = dww[c * 9 + j];
    const float bias = dwb[c];
    __syncthreads();
    for (int r = 0; r < 16; ++r) {
        const int idx = threadIdx.x + r * 256;
        const int h = idx >> 6, w = idx & 63;
        float acc = bias;
#pragma unroll
        for (int dh = 0; dh < 3; ++dh) {
            const int hh = h + dh - 1;
            if (hh < 0 || hh > 63) continue;
#pragma unroll
            for (int dw2 = 0; dw2 < 3; ++dw2) {
                const int ww2 = w + dw2 - 1;
                if (ww2 < 0 || ww2 > 63) continue;
                acc += sl[hh][ww2] * wk[dh * 3 + dw2];
            }
        }
        out[base + idx] = bf16_rne(acc);
    }
}

// grid NC: xh[n,c,h]=mean_w xL, xw[n,c,w]=mean_h xL
__global__ __launch_bounds__(256) void pool_kernel(const float* __restrict__ xL,
                                                   float* __restrict__ xh,
                                                   float* __restrict__ xw) {
    __shared__ float sl[64][65];
    const size_t base = (size_t)blockIdx.x * HW;
    for (int r = 0; r < 16; ++r) {
        const int idx = threadIdx.x + r * 256;
        sl[idx >> 6][idx & 63] = xL[base + idx];
    }
    __syncthreads();
    const int t = threadIdx.x;
    if (t < 64) {
        float s = 0.f;
        for (int w = 0; w < 64; ++w) s += sl[t][w];
        xh[(size_t)blockIdx.x * 64 + t] = s * (1.f / 64.f);
    } else if (t < 128) {
        const int w = t - 64;
        float s = 0.f;
        for (int h = 0; h < 64; ++h) s += sl[h][w];
        xw[(size_t)blockIdx.x * 64 + w] = s * (1.f / 64.f);
    }
}

// grid N: yc = relu(bn(la1 @ [xh;xw])); sh = sig(fh@yc_h), sw = sig(fw@yc_w)
__global__ __launch_bounds__(256) void local_att_kernel(const float* __restrict__ xh,
                                                        const float* __restrict__ xw,
                                                        const float* __restrict__ la1w,
                                                        const float* __restrict__ lag,
                                                        const float* __restrict__ lab,
                                                        const float* __restrict__ larm,
                                                        const float* __restrict__ larv,
                                                        const float* __restrict__ fhw,
                                                        const float* __restrict__ fww,
                                                        float* __restrict__ sh,
                                                        float* __restrict__ sw) {
    const int n = blockIdx.x;
    __shared__ float w1s[16 * 256];
    __shared__ float fhs[256 * 16];
    __shared__ float fws[256 * 16];
    __shared__ float ycs[16][128];
    for (int i = threadIdx.x; i < 4096; i += 256) {
        w1s[i] = la1w[i];
        fhs[i] = fhw[i];
        fws[i] = fww[i];
    }
    __syncthreads();
    for (int idx = threadIdx.x; idx < 2048; idx += 256) {
        const int m = idx >> 7, p = idx & 127;
        const float* vsrc = (p < 64) ? (xh + (size_t)n * CC * 64 + p)
                                     : (xw + (size_t)n * CC * 64 + (p - 64));
        float acc = 0.f;
#pragma unroll 8
        for (int c = 0; c < 256; ++c) acc += w1s[m * 256 + c] * vsrc[(size_t)c * 64];
        const float inv = lag[m] / sqrtf(larv[m] + 1e-5f);
        const float off = lab[m] - larm[m] * inv;
        ycs[m][p] = fmaxf(inv * acc + off, 0.f);
    }
    __syncthreads();
    for (int idx = threadIdx.x; idx < 16384; idx += 256) {
        const int c = idx >> 6, h = idx & 63;
        float a1 = 0.f, a2 = 0.f;
#pragma unroll
        for (int m = 0; m < 16; ++m) {
            a1 += fhs[c * 16 + m] * ycs[m][h];
            a2 += fws[c * 16 + m] * ycs[m][64 + h];
        }
        sh[(size_t)n * CC * 64 + idx] = sigmoidf_(a1);
        sw[(size_t)n * CC * 64 + idx] = sigmoidf_(a2);
    }
}

// grid NC: out = xL * sh[h]*sw[w]  (out-of-place: xL in workspace, out = d_out)
__global__ __launch_bounds__(256) void final_kernel(const float* __restrict__ xL,
                                                    const float* __restrict__ sh,
                                                    const float* __restrict__ sw,
                                                    float* __restrict__ out) {
    __shared__ float shs[64], sws[64];
    const int t = threadIdx.x;
    if (t < 64) shs[t] = sh[(size_t)blockIdx.x * 64 + t];
    else if (t < 128) sws[t - 64] = sw[(size_t)blockIdx.x * 64 + (t - 64)];
    __syncthreads();
    const size_t base = (size_t)blockIdx.x * HW;
#pragma unroll 4
    for (int r = 0; r < 16; ++r) {
        const int idx = t + r * 256;
        out[base + idx] = xL[base + idx] * shs[idx >> 6] * sws[idx & 63];
    }
}

extern "C" void kernel_launch(void* const* d_in, const int* in_sizes, int n_in,
                              void* d_out, int out_size, void* d_ws, size_t ws_size,
                              hipStream_t stream) {
    const float* x1 = (const float*)d_in[0];
    const float* x2 = (const float*)d_in[1];
    const float* c1w = (const float*)d_in[2];
    const float* c1b = (const float*)d_in[3];
    const float* c2w = (const float*)d_in[4];
    const float* c2b = (const float*)d_in[5];
    const float* c3w = (const float*)d_in[6];
    const float* c3b = (const float*)d_in[7];
    const float* c4w = (const float*)d_in[8];
    const float* c4b = (const float*)d_in[9];
    const float* cgw = (const float*)d_in[10];
    const float* cgb = (const float*)d_in[11];
    const float* bng = (const float*)d_in[12];
    const float* bnb = (const float*)d_in[13];
    const float* bnrm = (const float*)d_in[14];
    const float* bnrv = (const float*)d_in[15];
    const float* gamma = (const float*)d_in[16];
    const float* beta = (const float*)d_in[17];
    const float* gatew = (const float*)d_in[18];
    const float* gateb = (const float*)d_in[19];
    const float* dww = (const float*)d_in[20];
    const float* dwb = (const float*)d_in[21];
    // d_in[22], d_in[23]: interact_w/b — dead code (softmax over size-1 axis == 1)
    const float* caw = (const float*)d_in[24];
    const float* la1w = (const float*)d_in[25];
    const float* lag = (const float*)d_in[26];
    const float* lab = (const float*)d_in[27];
    const float* larm = (const float*)d_in[28];
    const float* larv = (const float*)d_in[29];
    const float* fhw = (const float*)d_in[30];
    const float* fww = (const float*)d_in[31];

    // ---- Workspace plan ----
    // buf0: g1 -> x_low (in place) -> dw split ushorts [n][HW][C]
    // buf1: [conv1 splits hi,mid] -> XG (alive through gemm_final)
    // buf2: [conv1/conv2 lo split] -> dw bf16 [n][C][HW] -> xL (gemm_final out)
    // d_out: [conv2 splits hi,mid] -> [x_up splits hi,lo] -> final out
    float* ws = (float*)d_ws;
    float* buf0 = ws;
    float* buf1 = ws + FSZ;
    float* buf2 = ws + 2 * FSZ;
    float* sp = ws + 3 * FSZ;
    float* sum_c = sp;    sp += 4096;   // later reused as gate
    float* sq_c = sp;     sp += 4096;   // contiguous with sum_c (zeroed together)
    float* rw = sp;       sp += 4096;
    float* ca_sig = sp;   sp += 4096;
    float* xlow_sum = sp; sp += 4096;
    float* mu_g = sp;     sp += 256;
    float* isd_g = sp;    sp += 256;
    float* s_pix = sp;    sp += (size_t)NN * HW;       // 65536, raw (pre-sigmoid)
    float* xh = sp;       sp += (size_t)NN * CC * 64;  // 262144
    float* xwb = sp;      sp += (size_t)NN * CC * 64;
    float* shb = sp;      sp += (size_t)NN * CC * 64;
    float* swb = sp;      sp += (size_t)NN * CC * 64;
    // weight splits overlap shb/swb (written only at step 10; weights dead by then)
    unsigned short* wsp = (unsigned short*)shb;
    unsigned short* w1h = wsp + 0 * 65536;
    unsigned short* w1m = wsp + 1 * 65536;
    unsigned short* w1l = wsp + 2 * 65536;
    unsigned short* w2h = wsp + 3 * 65536;
    unsigned short* w2m = wsp + 4 * 65536;
    unsigned short* w2l = wsp + 5 * 65536;
    unsigned short* w4h = wsp + 6 * 65536;
    unsigned short* w4l = wsp + 7 * 65536;
    unsigned short* w3b = wsp + 8 * 65536;

    float* out = (float*)d_out;

    const dim3 gt(HW / 64, CC / 64, NN);   // tsplit/masks grids (64, 4, 16)
    const dim3 gg(HW / 64, CC / 128, NN);  // gemm grids (64, 2, 16)

    // 0: weight splits (fragment order) + zero sum_c/sq_c and s_pix accumulators
    wsplit_kernel<<<256, 256, 0, stream>>>(c1w, c2w, c3w, c4w, w1h, w1m, w1l,
                                           w2h, w2m, w2l, w4h, w4l, w3b,
                                           sum_c, s_pix);
    // 1: g1 = conv1(x1)  (3-split ~fp32 MFMA). Splits: buf1 (hi,mid) + buf2 (lo).
    {
        unsigned short* sx0 = (unsigned short*)buf1;
        unsigned short* sx1 = (unsigned short*)buf1 + FSZ;
        unsigned short* sx2 = (unsigned short*)buf2;
        tsplit3_kernel<<<gt, 256, 0, stream>>>(x1, sx0, sx1, sx2);
        gemm_mfma_kernel<<<gg, 256, 0, stream>>>(sx0, sx1, sx2, w1h, w1m, w1l, c1b, buf0);
    }
    // 2: XG = conv2(x2) + g1 fused. Splits: d_out (hi,mid) + buf2 (lo).
    //    Epilogue also accumulates sum_c/sq_c (XG stats) and s_pix (conv4g dot).
    {
        unsigned short* sx0 = (unsigned short*)out;
        unsigned short* sx1 = (unsigned short*)out + FSZ;
        unsigned short* sx2 = (unsigned short*)buf2;
        tsplit3_kernel<<<gt, 256, 0, stream>>>(x2, sx0, sx1, sx2);
        gemm_xg_kernel<<<gg, 256, 0, stream>>>(sx0, sx1, sx2, w2h, w2m, w2l, c2b,
                                               buf0, cgw, buf1, sum_c, sq_c, s_pix);
    }
    // 3: rw, channel-att sigmoid, group mu/invsd (+ zero xlow_sum)
    stats2_kernel<<<NN, 256, 0, stream>>>(sum_c, sq_c, caw, rw, ca_sig, mu_g, isd_g, xlow_sum);
    // 4: fused masks + conv4-input split (g2 = XG - g1): x_low -> buf0 (in place),
    //    x_up splits -> d_out, xlow_sum via atomics (zeroed in step 3)
    {
        unsigned short* ux0 = (unsigned short*)out;
        unsigned short* ux1 = (unsigned short*)out + FSZ;
        masks_split_kernel<<<gt, 256, 0, stream>>>(buf0, buf1, rw, bng, bnb, bnrm, bnrv,
                                                   ux0, ux1, xlow_sum);
    }
    // 5: gate softmax (output reuses sum_c)
    float* gate = sum_c;
    gate_kernel<<<NN, 256, 0, stream>>>(xlow_sum, gatew, gateb, gate);
    // 6: dwconv on x_low (buf0) -> bf16 [n][C][HW] in buf2 (lo splits dead)
    dwconv_kernel<<<NN * CC, 256, 0, stream>>>(buf0, dww, dwb, (unsigned short*)buf2);
    // 7: transpose dw bf16 -> [n][HW][C] split in buf0 (x_low dead)
    tsplit_bf16_kernel<<<gt, 256, 0, stream>>>((const unsigned short*)buf2,
                                               (unsigned short*)buf0);
    // 8: merged conv4+conv3 GEMM + final combine -> xL in buf2 (dw bf16 dead).
    //    Reads x_up splits (d_out), dw split (buf0), XG (buf1).
    {
        unsigned short* ux0 = (unsigned short*)out;
        unsigned short* ux1 = (unsigned short*)out + FSZ;
        unsigned short* sx0 = (unsigned short*)buf0;
        gemm_final_kernel<<<gg, 256, 0, stream>>>(ux0, ux1, sx0, w4h, w4l, w3b,
                                                  c3b, c4b, buf1, s_pix, cgb,
                                                  gate, ca_sig, mu_g, isd_g, gamma, beta,
                                                  buf2);
    }
    // 9: pools (read xL from buf2)
    pool_kernel<<<NN * CC, 256, 0, stream>>>(buf2, xh, xwb);
    // 10: coordinate attention -> sh, sw (overwrites weight-split region — weights dead)
    local_att_kernel<<<NN, 256, 0, stream>>>(xh, xwb, la1w, lag, lab, larm, larv,
                                             fhw, fww, shb, swb);
    // 11: out = xL * sh*sw  (buf2 -> d_out; x_up splits in d_out are dead)
    final_kernel<<<NN * CC, 256, 0, stream>>>(buf2, shb, swb, out);
}